// Round 1
// baseline (436.345 us; speedup 1.0000x reference)
//
#include <hip/hip_runtime.h>
#include <cmath>

#define NS 88
#define NL 10
#define NT 30
#define NE 768
#define NH 64
#define NG 256   // 4*H
#define NM 300   // L*T

// ---------------------------------------------------------------------------
// Kernel 1: u[s,m,n] = sum_e text[s,m,e] * Uall_w[s,e,n] + Uall_b[s,n]
// m = l*T + t in [0,300), n in [0,256). Tiled fp32 GEMM, 64x64 tile, 4x4/thr.
// ---------------------------------------------------------------------------
__global__ __launch_bounds__(256) void gemm_u_kernel(
    const float* __restrict__ Atext,   // [S, 300, 768]
    const float* __restrict__ Bw,      // [S, 768, 256]
    const float* __restrict__ bias,    // [S, 256]
    float* __restrict__ U)             // [S, 300, 256]
{
  int bid = blockIdx.x;
  int s   = bid / 20;
  int rem = bid % 20;
  int m0  = (rem / 4) * 64;
  int n0  = (rem % 4) * 64;

  const float* A = Atext + (size_t)s * NM * NE;
  const float* B = Bw    + (size_t)s * NE * NG;

  __shared__ float As[64][17];   // +1 pad breaks 16-way bank conflict
  __shared__ float Bs[16][64];

  int t  = threadIdx.x;
  int ty = t >> 4, tx = t & 15;        // compute mapping: 16x16 threads
  int ar = t >> 2, ac = (t & 3) << 2;  // A load: 64 rows x 16 cols, float4
  int br = t >> 4, bc = (t & 15) << 2; // B load: 16 rows x 64 cols, float4

  float acc[4][4] = {{0.f,0.f,0.f,0.f},{0.f,0.f,0.f,0.f},
                     {0.f,0.f,0.f,0.f},{0.f,0.f,0.f,0.f}};

  for (int k0 = 0; k0 < NE; k0 += 16) {
    if (m0 + ar < NM) {
      float4 av = *(const float4*)(A + (size_t)(m0 + ar) * NE + (k0 + ac));
      As[ar][ac+0] = av.x; As[ar][ac+1] = av.y;
      As[ar][ac+2] = av.z; As[ar][ac+3] = av.w;
    } else {
      As[ar][ac+0] = 0.f; As[ar][ac+1] = 0.f;
      As[ar][ac+2] = 0.f; As[ar][ac+3] = 0.f;
    }
    *(float4*)(&Bs[br][bc]) =
        *(const float4*)(B + (size_t)(k0 + br) * NG + (n0 + bc));
    __syncthreads();
#pragma unroll
    for (int kk = 0; kk < 16; ++kk) {
      float a0 = As[ty*4+0][kk], a1 = As[ty*4+1][kk];
      float a2 = As[ty*4+2][kk], a3 = As[ty*4+3][kk];
      float4 b = *(const float4*)(&Bs[kk][tx*4]);
      acc[0][0] = fmaf(a0, b.x, acc[0][0]);
      acc[0][1] = fmaf(a0, b.y, acc[0][1]);
      acc[0][2] = fmaf(a0, b.z, acc[0][2]);
      acc[0][3] = fmaf(a0, b.w, acc[0][3]);
      acc[1][0] = fmaf(a1, b.x, acc[1][0]);
      acc[1][1] = fmaf(a1, b.y, acc[1][1]);
      acc[1][2] = fmaf(a1, b.z, acc[1][2]);
      acc[1][3] = fmaf(a1, b.w, acc[1][3]);
      acc[2][0] = fmaf(a2, b.x, acc[2][0]);
      acc[2][1] = fmaf(a2, b.y, acc[2][1]);
      acc[2][2] = fmaf(a2, b.z, acc[2][2]);
      acc[2][3] = fmaf(a2, b.w, acc[2][3]);
      acc[3][0] = fmaf(a3, b.x, acc[3][0]);
      acc[3][1] = fmaf(a3, b.y, acc[3][1]);
      acc[3][2] = fmaf(a3, b.z, acc[3][2]);
      acc[3][3] = fmaf(a3, b.w, acc[3][3]);
    }
    __syncthreads();
  }

  float4 bv = *(const float4*)(bias + (size_t)s * NG + n0 + tx*4);
#pragma unroll
  for (int i = 0; i < 4; ++i) {
    int m = m0 + ty*4 + i;
    if (m < NM) {
      float4 o;
      o.x = acc[i][0] + bv.x; o.y = acc[i][1] + bv.y;
      o.z = acc[i][2] + bv.z; o.w = acc[i][3] + bv.w;
      *(float4*)(U + ((size_t)s * NM + m) * NG + n0 + tx*4) = o;
    }
  }
}

// ---------------------------------------------------------------------------
// Kernel 2: TimeLSTM scan over T. One block per stock; 256 threads.
// Thread g owns Wall column g (64 regs) and Wd column g%64 (64 regs).
// State h,c [L][H] in LDS. All-sigmoid gates (f,i,o,g order per reference).
// ---------------------------------------------------------------------------
__global__ __launch_bounds__(256) void time_lstm_kernel(
    const float* __restrict__ u,       // [S, L*T, 256]
    const float* __restrict__ time_in, // [S, L, T]
    const float* __restrict__ Wdw,     // [S, H, H]
    const float* __restrict__ Wdb,     // [S, H]
    const float* __restrict__ Wallw,   // [S, H, 4H]
    const float* __restrict__ Wallb,   // [S, 4H]
    float* __restrict__ full)          // [S, L, T, H]
{
  int s = blockIdx.x;
  int g = threadIdx.x;
  int j = g & 63;
  int q = g >> 6;

  float wall[NH];
#pragma unroll
  for (int k = 0; k < NH; ++k)
    wall[k] = Wallw[((size_t)s * NH + k) * NG + g];
  float wallb = Wallb[(size_t)s * NG + g];

  float wd[NH];
#pragma unroll
  for (int k = 0; k < NH; ++k)
    wd[k] = Wdw[((size_t)s * NH + k) * NH + j];
  float wdb = Wdb[(size_t)s * NH + j];

  __shared__ float h_s[NL][NH];
  __shared__ float c_s[NL][NH];
  __shared__ float cadj[NL][NH];
  __shared__ float gsig[NL][NG];

  for (int l = q; l < NL; l += 4) { h_s[l][j] = 0.f; c_s[l][j] = 0.f; }
  __syncthreads();

  for (int t = 0; t < NT; ++t) {
    // c_s1 = tanh(c @ Wd + b); c_adj = c + c_s1*(ts-1)
    for (int l = q; l < NL; l += 4) {
      float acc = wdb;
#pragma unroll
      for (int k = 0; k < NH; ++k) acc = fmaf(c_s[l][k], wd[k], acc);
      float cs1 = tanhf(acc);
      float ts  = time_in[((size_t)s * NL + l) * NT + t];
      cadj[l][j] = c_s[l][j] + cs1 * (ts - 1.f);
    }
    // gates = sigmoid(h @ Wall + b + u_t)
    for (int l = 0; l < NL; ++l) {
      float acc = wallb + u[(((size_t)s * NL + l) * NT + t) * NG + g];
#pragma unroll
      for (int k = 0; k < NH; ++k) acc = fmaf(h_s[l][k], wall[k], acc);
      gsig[l][g] = 1.f / (1.f + expf(-acc));
    }
    __syncthreads();
    // c = f*c_adj + i*g ; h = o*tanh(c)   (f,i,o,g slices)
    for (int l = q; l < NL; l += 4) {
      float f  = gsig[l][j];
      float ii = gsig[l][64 + j];
      float o  = gsig[l][128 + j];
      float gg = gsig[l][192 + j];
      float cn = fmaf(f, cadj[l][j], ii * gg);
      c_s[l][j] = cn;
      float hn = o * tanhf(cn);
      h_s[l][j] = hn;
      full[(((size_t)s * NL + l) * NT + t) * NH + j] = hn;
    }
    __syncthreads();
  }
}

// ---------------------------------------------------------------------------
// Kernel 3: text attention over T. One block (64 thr = 1 wave) per (s,l).
// ---------------------------------------------------------------------------
__global__ __launch_bounds__(64) void text_attn_kernel(
    const float* __restrict__ full,   // [S, L, T, H]
    const float* __restrict__ tW1w, const float* __restrict__ tW1b,
    const float* __restrict__ tW2w, const float* __restrict__ tW2b,
    const float* __restrict__ tVw,  const float* __restrict__ tVb,
    float* __restrict__ day_vec)      // [S, L, H]
{
  int bid = blockIdx.x;            // s*L + l
  int s = bid / NL;
  int k = threadIdx.x;             // 0..63

  __shared__ float fl[NT][NH];
  const float* fp = full + (size_t)bid * NT * NH;
  for (int i = k; i < NT * NH; i += 64) ((float*)fl)[i] = fp[i];

  float tw2[NH];
#pragma unroll
  for (int h = 0; h < NH; ++h)
    tw2[h] = tW2w[((size_t)s * NH + h) * NH + k];
  __syncthreads();

  // a1[k] = h_last @ tW1 col k + b
  float a1 = tW1b[(size_t)s * NH + k];
#pragma unroll
  for (int h = 0; h < NH; ++h)
    a1 = fmaf(fl[NT-1][h], tW1w[((size_t)s * NH + h) * NH + k], a1);

  float b2k = tW2b[(size_t)s * NH + k];
  float tv  = tVw[(size_t)s * NH + k];
  float tvb = tVb[s];

  float score[NT];
#pragma unroll
  for (int t = 0; t < NT; ++t) {
    float a2 = b2k;
#pragma unroll
    for (int h = 0; h < NH; ++h) a2 = fmaf(fl[t][h], tw2[h], a2);
    float v = tanhf(a1 + a2) * tv;
#pragma unroll
    for (int off = 32; off >= 1; off >>= 1) v += __shfl_xor(v, off);
    score[t] = v + tvb;
  }
  // softmax over T (identical in all lanes)
  float mx = score[0];
#pragma unroll
  for (int t = 1; t < NT; ++t) mx = fmaxf(mx, score[t]);
  float sum = 0.f;
#pragma unroll
  for (int t = 0; t < NT; ++t) { score[t] = expf(score[t] - mx); sum += score[t]; }
  float inv = 1.f / sum;
  float dv = 0.f;
#pragma unroll
  for (int t = 0; t < NT; ++t) dv = fmaf(score[t] * inv, fl[t][k], dv);
  day_vec[(size_t)bid * NH + k] = dv;
}

// ---------------------------------------------------------------------------
// Kernel 4: day LSTM (single step from zero state, torch i,f,g,o order) +
// day attention over L + shared pred head. One block per stock.
// ---------------------------------------------------------------------------
__global__ __launch_bounds__(256) void day_head_kernel(
    const float* __restrict__ day_vec, // [S, L, H]
    const float* __restrict__ ihw, const float* __restrict__ ihb,
    const float* __restrict__ hhb,
    const float* __restrict__ dW1w, const float* __restrict__ dW1b,
    const float* __restrict__ dW2w, const float* __restrict__ dW2b,
    const float* __restrict__ dVw,  const float* __restrict__ dVb,
    const float* __restrict__ predw, const float* __restrict__ predb,
    float* __restrict__ out)           // [S]
{
  int s = blockIdx.x;
  int g = threadIdx.x;
  int j = g & 63;
  int q = g >> 6;

  __shared__ float dv_s[NL][NH];
  __shared__ float gl[NL][NG];
  __shared__ float hd[NL][NH];

  for (int i = g; i < NL * NH; i += 256)
    ((float*)dv_s)[i] = day_vec[(size_t)s * NL * NH + i];
  __syncthreads();

  float ihcol[NH];
#pragma unroll
  for (int k = 0; k < NH; ++k)
    ihcol[k] = ihw[((size_t)s * NH + k) * NG + g];
  float bias = ihb[(size_t)s * NG + g] + hhb[(size_t)s * NG + g];

  bool is_gpart = (g >= 128 && g < 192);
  for (int l = 0; l < NL; ++l) {
    float acc = bias;
#pragma unroll
    for (int k = 0; k < NH; ++k) acc = fmaf(dv_s[l][k], ihcol[k], acc);
    gl[l][g] = is_gpart ? tanhf(acc) : 1.f / (1.f + expf(-acc));
  }
  __syncthreads();
  for (int l = q; l < NL; l += 4) {
    float cd = gl[l][j] * gl[l][128 + j];       // sig(i)*tanh(g)
    hd[l][j] = gl[l][192 + j] * tanhf(cd);      // sig(o)*tanh(c)
  }
  __syncthreads();

  if (g < 64) {
    int k = g;
    float dw1c[NH], dw2c[NH];
#pragma unroll
    for (int h = 0; h < NH; ++h) {
      dw1c[h] = dW1w[((size_t)s * NH + h) * NH + k];
      dw2c[h] = dW2w[((size_t)s * NH + h) * NH + k];
    }
    float b1 = dW1b[(size_t)s * NH + k];
    float b2 = dW2b[(size_t)s * NH + k];
    float dv = dVw[(size_t)s * NH + k];
    float dvb = dVb[s];

    float sc[NL];
#pragma unroll
    for (int l = 0; l < NL; ++l) {
      float x1 = b1, x2 = b2;
#pragma unroll
      for (int h = 0; h < NH; ++h) {
        x1 = fmaf(hd[l][h], dw1c[h], x1);
        x2 = fmaf(hd[l][h], dw2c[h], x2);
      }
      float v = tanhf(x1 + x2) * dv;
#pragma unroll
      for (int off = 32; off >= 1; off >>= 1) v += __shfl_xor(v, off);
      sc[l] = v + dvb;
    }
    float mx = sc[0];
#pragma unroll
    for (int l = 1; l < NL; ++l) mx = fmaxf(mx, sc[l]);
    float sum = 0.f;
#pragma unroll
    for (int l = 0; l < NL; ++l) { sc[l] = expf(sc[l] - mx); sum += sc[l]; }
    float inv = 1.f / sum;
    float sv = 0.f;
#pragma unroll
    for (int l = 0; l < NL; ++l) sv = fmaf(sc[l] * inv, hd[l][k], sv);

    float p = sv * predw[k];
#pragma unroll
    for (int off = 32; off >= 1; off >>= 1) p += __shfl_xor(p, off);
    if (k == 0) {
      float x = p + predb[0];
      out[s] = (x >= 0.f) ? x : 0.01f * x;
    }
  }
}

// ---------------------------------------------------------------------------
extern "C" void kernel_launch(void* const* d_in, const int* in_sizes, int n_in,
                              void* d_out, int out_size, void* d_ws, size_t ws_size,
                              hipStream_t stream) {
  (void)in_sizes; (void)n_in; (void)out_size; (void)ws_size;

  const float* text    = (const float*)d_in[0];
  const float* time_in = (const float*)d_in[1];
  const float* Wdw     = (const float*)d_in[2];
  const float* Wdb     = (const float*)d_in[3];
  const float* Wallw   = (const float*)d_in[4];
  const float* Wallb   = (const float*)d_in[5];
  const float* Uallw   = (const float*)d_in[6];
  const float* Uallb   = (const float*)d_in[7];
  const float* tW1w    = (const float*)d_in[8];
  const float* tW1b    = (const float*)d_in[9];
  const float* tW2w    = (const float*)d_in[10];
  const float* tW2b    = (const float*)d_in[11];
  const float* tVw     = (const float*)d_in[12];
  const float* tVb     = (const float*)d_in[13];
  const float* ihw     = (const float*)d_in[14];
  const float* ihb     = (const float*)d_in[15];
  const float* hhb     = (const float*)d_in[16];
  const float* dW1w    = (const float*)d_in[17];
  const float* dW1b    = (const float*)d_in[18];
  const float* dW2w    = (const float*)d_in[19];
  const float* dW2b    = (const float*)d_in[20];
  const float* dVw     = (const float*)d_in[21];
  const float* dVb     = (const float*)d_in[22];
  const float* predw   = (const float*)d_in[23];
  const float* predb   = (const float*)d_in[24];

  float* ws      = (float*)d_ws;
  float* u       = ws;                              // S*300*256 = 6,758,400
  float* full    = u + (size_t)NS * NM * NG;        // S*L*T*H   = 1,689,600
  float* day_vec = full + (size_t)NS * NL * NT * NH;// S*L*H     =    56,320

  gemm_u_kernel<<<NS * 20, 256, 0, stream>>>(text, Uallw, Uallb, u);
  time_lstm_kernel<<<NS, 256, 0, stream>>>(u, time_in, Wdw, Wdb, Wallw, Wallb, full);
  text_attn_kernel<<<NS * NL, 64, 0, stream>>>(full, tW1w, tW1b, tW2w, tW2b,
                                               tVw, tVb, day_vec);
  day_head_kernel<<<NS, 256, 0, stream>>>(day_vec, ihw, ihb, hhb,
                                          dW1w, dW1b, dW2w, dW2b, dVw, dVb,
                                          predw, predb, (float*)d_out);
}

// Round 2
// 289.533 us; speedup vs baseline: 1.5071x; 1.5071x over previous
//
#include <hip/hip_runtime.h>
#include <cmath>

#define NS 88
#define NL 10
#define NT 30
#define NE 768
#define NH 64
#define NG 256   // 4*H
#define NM 300   // L*T

// ---------------------------------------------------------------------------
// Kernel 1: u[s,m,n] = sum_e text[s,m,e] * Uall_w[s,e,n] + Uall_b[s,n]
// m = l*T + t in [0,300), n in [0,256). Tiled fp32 GEMM, 64x64 tile, 4x4/thr.
// ---------------------------------------------------------------------------
__global__ __launch_bounds__(256) void gemm_u_kernel(
    const float* __restrict__ Atext,   // [S, 300, 768]
    const float* __restrict__ Bw,      // [S, 768, 256]
    const float* __restrict__ bias,    // [S, 256]
    float* __restrict__ U)             // [S, 300, 256]
{
  int bid = blockIdx.x;
  int s   = bid / 20;
  int rem = bid % 20;
  int m0  = (rem / 4) * 64;
  int n0  = (rem % 4) * 64;

  const float* A = Atext + (size_t)s * NM * NE;
  const float* B = Bw    + (size_t)s * NE * NG;

  __shared__ float As[64][17];   // +1 pad breaks 16-way bank conflict
  __shared__ float Bs[16][64];

  int t  = threadIdx.x;
  int ty = t >> 4, tx = t & 15;        // compute mapping: 16x16 threads
  int ar = t >> 2, ac = (t & 3) << 2;  // A load: 64 rows x 16 cols, float4
  int br = t >> 4, bc = (t & 15) << 2; // B load: 16 rows x 64 cols, float4

  float acc[4][4] = {{0.f,0.f,0.f,0.f},{0.f,0.f,0.f,0.f},
                     {0.f,0.f,0.f,0.f},{0.f,0.f,0.f,0.f}};

  for (int k0 = 0; k0 < NE; k0 += 16) {
    if (m0 + ar < NM) {
      float4 av = *(const float4*)(A + (size_t)(m0 + ar) * NE + (k0 + ac));
      As[ar][ac+0] = av.x; As[ar][ac+1] = av.y;
      As[ar][ac+2] = av.z; As[ar][ac+3] = av.w;
    } else {
      As[ar][ac+0] = 0.f; As[ar][ac+1] = 0.f;
      As[ar][ac+2] = 0.f; As[ar][ac+3] = 0.f;
    }
    *(float4*)(&Bs[br][bc]) =
        *(const float4*)(B + (size_t)(k0 + br) * NG + (n0 + bc));
    __syncthreads();
#pragma unroll
    for (int kk = 0; kk < 16; ++kk) {
      float a0 = As[ty*4+0][kk], a1 = As[ty*4+1][kk];
      float a2 = As[ty*4+2][kk], a3 = As[ty*4+3][kk];
      float4 b = *(const float4*)(&Bs[kk][tx*4]);
      acc[0][0] = fmaf(a0, b.x, acc[0][0]);
      acc[0][1] = fmaf(a0, b.y, acc[0][1]);
      acc[0][2] = fmaf(a0, b.z, acc[0][2]);
      acc[0][3] = fmaf(a0, b.w, acc[0][3]);
      acc[1][0] = fmaf(a1, b.x, acc[1][0]);
      acc[1][1] = fmaf(a1, b.y, acc[1][1]);
      acc[1][2] = fmaf(a1, b.z, acc[1][2]);
      acc[1][3] = fmaf(a1, b.w, acc[1][3]);
      acc[2][0] = fmaf(a2, b.x, acc[2][0]);
      acc[2][1] = fmaf(a2, b.y, acc[2][1]);
      acc[2][2] = fmaf(a2, b.z, acc[2][2]);
      acc[2][3] = fmaf(a2, b.w, acc[2][3]);
      acc[3][0] = fmaf(a3, b.x, acc[3][0]);
      acc[3][1] = fmaf(a3, b.y, acc[3][1]);
      acc[3][2] = fmaf(a3, b.z, acc[3][2]);
      acc[3][3] = fmaf(a3, b.w, acc[3][3]);
    }
    __syncthreads();
  }

  float4 bv = *(const float4*)(bias + (size_t)s * NG + n0 + tx*4);
#pragma unroll
  for (int i = 0; i < 4; ++i) {
    int m = m0 + ty*4 + i;
    if (m < NM) {
      float4 o;
      o.x = acc[i][0] + bv.x; o.y = acc[i][1] + bv.y;
      o.z = acc[i][2] + bv.z; o.w = acc[i][3] + bv.w;
      *(float4*)(U + ((size_t)s * NM + m) * NG + n0 + tx*4) = o;
    }
  }
}

// ---------------------------------------------------------------------------
// Kernel 2: TimeLSTM scan over T. One block per (stock, lookback-day):
// 880 blocks x 320 threads (5 waves). Waves 0-3 own the 256 gate columns
// (Wall col in regs); wave 4 owns the 64 Wd columns. State h,c [H] in LDS.
// u_t prefetched one step ahead into registers. 2 barriers/step.
// ---------------------------------------------------------------------------
__global__ __launch_bounds__(320) void time_lstm_kernel(
    const float* __restrict__ u,       // [S, L*T, 256]
    const float* __restrict__ time_in, // [S, L, T]
    const float* __restrict__ Wdw,     // [S, H, H]
    const float* __restrict__ Wdb,     // [S, H]
    const float* __restrict__ Wallw,   // [S, H, 4H]
    const float* __restrict__ Wallb,   // [S, 4H]
    float* __restrict__ full)          // [S, L, T, H]
{
  int bid = blockIdx.x;                // s*NL + l
  int s = bid / NL;
  int g = threadIdx.x;                 // 0..319
  bool is_gate = (g < NG);

  // unified weight column: Wall col g (gate threads) or Wd col g-256 (wave 4)
  float wcol[NH];
  float wbias;
  if (is_gate) {
#pragma unroll
    for (int k = 0; k < NH; ++k)
      wcol[k] = Wallw[((size_t)s * NH + k) * NG + g];
    wbias = Wallb[(size_t)s * NG + g];
  } else {
    int j = g - NG;
#pragma unroll
    for (int k = 0; k < NH; ++k)
      wcol[k] = Wdw[((size_t)s * NH + k) * NH + j];
    wbias = Wdb[(size_t)s * NH + j];
  }

  __shared__ float h_s[NH];
  __shared__ float c_s[NH];
  __shared__ float cadj_s[NH];
  __shared__ float gates_s[NG];
  __shared__ float ts_s[NT];

  const float* u_base    = u + (size_t)bid * NT * NG;
  float*       full_base = full + (size_t)bid * NT * NH;

  if (g < NH) { h_s[g] = 0.f; c_s[g] = 0.f; }
  if (g < NT) ts_s[g] = time_in[(size_t)bid * NT + g];

  float u_next = is_gate ? u_base[g] : 0.f;   // prefetch t=0
  __syncthreads();

  for (int t = 0; t < NT; ++t) {
    float u_cur = u_next;
    if (is_gate && t + 1 < NT) u_next = u_base[(size_t)(t + 1) * NG + g];

    // dot(wcol, h) for gate threads; dot(wcol, c) for wd threads.
    const float4* src4 = (const float4*)(is_gate ? h_s : c_s);
    float a0 = 0.f, a1 = 0.f, a2 = 0.f, a3 = 0.f;
#pragma unroll
    for (int k4 = 0; k4 < NH / 4; ++k4) {
      float4 v = src4[k4];
      a0 = fmaf(v.x, wcol[4 * k4 + 0], a0);
      a1 = fmaf(v.y, wcol[4 * k4 + 1], a1);
      a2 = fmaf(v.z, wcol[4 * k4 + 2], a2);
      a3 = fmaf(v.w, wcol[4 * k4 + 3], a3);
    }
    float dot = ((a0 + a1) + (a2 + a3)) + wbias;

    if (is_gate) {
      float acc = dot + u_cur;
      gates_s[g] = 1.f / (1.f + expf(-acc));        // all-sigmoid per reference
    } else {
      int j = g - NG;
      float cs1 = tanhf(dot);
      cadj_s[j] = c_s[j] + cs1 * (ts_s[t] - 1.f);   // c - cs1 + cs1*ts
    }
    __syncthreads();

    if (g < NH) {                                   // f,i,o,g slice order
      float f  = gates_s[g];
      float ii = gates_s[NH + g];
      float o  = gates_s[2 * NH + g];
      float gg = gates_s[3 * NH + g];
      float cn = fmaf(f, cadj_s[g], ii * gg);
      c_s[g] = cn;
      float hn = o * tanhf(cn);
      h_s[g] = hn;
      full_base[(size_t)t * NH + g] = hn;
    }
    __syncthreads();
  }
}

// ---------------------------------------------------------------------------
// Kernel 3: text attention over T. One block (64 thr = 1 wave) per (s,l).
// ---------------------------------------------------------------------------
__global__ __launch_bounds__(64) void text_attn_kernel(
    const float* __restrict__ full,   // [S, L, T, H]
    const float* __restrict__ tW1w, const float* __restrict__ tW1b,
    const float* __restrict__ tW2w, const float* __restrict__ tW2b,
    const float* __restrict__ tVw,  const float* __restrict__ tVb,
    float* __restrict__ day_vec)      // [S, L, H]
{
  int bid = blockIdx.x;            // s*L + l
  int s = bid / NL;
  int k = threadIdx.x;             // 0..63

  __shared__ float fl[NT][NH];
  const float* fp = full + (size_t)bid * NT * NH;
  for (int i = k; i < NT * NH; i += 64) ((float*)fl)[i] = fp[i];

  float tw2[NH];
#pragma unroll
  for (int h = 0; h < NH; ++h)
    tw2[h] = tW2w[((size_t)s * NH + h) * NH + k];
  __syncthreads();

  // a1[k] = h_last @ tW1 col k + b
  float a1 = tW1b[(size_t)s * NH + k];
#pragma unroll
  for (int h = 0; h < NH; ++h)
    a1 = fmaf(fl[NT-1][h], tW1w[((size_t)s * NH + h) * NH + k], a1);

  float b2k = tW2b[(size_t)s * NH + k];
  float tv  = tVw[(size_t)s * NH + k];
  float tvb = tVb[s];

  float score[NT];
#pragma unroll
  for (int t = 0; t < NT; ++t) {
    float a2 = b2k;
#pragma unroll
    for (int h = 0; h < NH; ++h) a2 = fmaf(fl[t][h], tw2[h], a2);
    float v = tanhf(a1 + a2) * tv;
#pragma unroll
    for (int off = 32; off >= 1; off >>= 1) v += __shfl_xor(v, off);
    score[t] = v + tvb;
  }
  // softmax over T (identical in all lanes)
  float mx = score[0];
#pragma unroll
  for (int t = 1; t < NT; ++t) mx = fmaxf(mx, score[t]);
  float sum = 0.f;
#pragma unroll
  for (int t = 0; t < NT; ++t) { score[t] = expf(score[t] - mx); sum += score[t]; }
  float inv = 1.f / sum;
  float dv = 0.f;
#pragma unroll
  for (int t = 0; t < NT; ++t) dv = fmaf(score[t] * inv, fl[t][k], dv);
  day_vec[(size_t)bid * NH + k] = dv;
}

// ---------------------------------------------------------------------------
// Kernel 4: day LSTM (single step from zero state, torch i,f,g,o order) +
// day attention over L + shared pred head. One block per stock.
// ---------------------------------------------------------------------------
__global__ __launch_bounds__(256) void day_head_kernel(
    const float* __restrict__ day_vec, // [S, L, H]
    const float* __restrict__ ihw, const float* __restrict__ ihb,
    const float* __restrict__ hhb,
    const float* __restrict__ dW1w, const float* __restrict__ dW1b,
    const float* __restrict__ dW2w, const float* __restrict__ dW2b,
    const float* __restrict__ dVw,  const float* __restrict__ dVb,
    const float* __restrict__ predw, const float* __restrict__ predb,
    float* __restrict__ out)           // [S]
{
  int s = blockIdx.x;
  int g = threadIdx.x;
  int j = g & 63;
  int q = g >> 6;

  __shared__ float dv_s[NL][NH];
  __shared__ float gl[NL][NG];
  __shared__ float hd[NL][NH];

  for (int i = g; i < NL * NH; i += 256)
    ((float*)dv_s)[i] = day_vec[(size_t)s * NL * NH + i];
  __syncthreads();

  float ihcol[NH];
#pragma unroll
  for (int k = 0; k < NH; ++k)
    ihcol[k] = ihw[((size_t)s * NH + k) * NG + g];
  float bias = ihb[(size_t)s * NG + g] + hhb[(size_t)s * NG + g];

  bool is_gpart = (g >= 128 && g < 192);
  for (int l = 0; l < NL; ++l) {
    float acc = bias;
#pragma unroll
    for (int k = 0; k < NH; ++k) acc = fmaf(dv_s[l][k], ihcol[k], acc);
    gl[l][g] = is_gpart ? tanhf(acc) : 1.f / (1.f + expf(-acc));
  }
  __syncthreads();
  for (int l = q; l < NL; l += 4) {
    float cd = gl[l][j] * gl[l][128 + j];       // sig(i)*tanh(g)
    hd[l][j] = gl[l][192 + j] * tanhf(cd);      // sig(o)*tanh(c)
  }
  __syncthreads();

  if (g < 64) {
    int k = g;
    float dw1c[NH], dw2c[NH];
#pragma unroll
    for (int h = 0; h < NH; ++h) {
      dw1c[h] = dW1w[((size_t)s * NH + h) * NH + k];
      dw2c[h] = dW2w[((size_t)s * NH + h) * NH + k];
    }
    float b1 = dW1b[(size_t)s * NH + k];
    float b2 = dW2b[(size_t)s * NH + k];
    float dv = dVw[(size_t)s * NH + k];
    float dvb = dVb[s];

    float sc[NL];
#pragma unroll
    for (int l = 0; l < NL; ++l) {
      float x1 = b1, x2 = b2;
#pragma unroll
      for (int h = 0; h < NH; ++h) {
        x1 = fmaf(hd[l][h], dw1c[h], x1);
        x2 = fmaf(hd[l][h], dw2c[h], x2);
      }
      float v = tanhf(x1 + x2) * dv;
#pragma unroll
      for (int off = 32; off >= 1; off >>= 1) v += __shfl_xor(v, off);
      sc[l] = v + dvb;
    }
    float mx = sc[0];
#pragma unroll
    for (int l = 1; l < NL; ++l) mx = fmaxf(mx, sc[l]);
    float sum = 0.f;
#pragma unroll
    for (int l = 0; l < NL; ++l) { sc[l] = expf(sc[l] - mx); sum += sc[l]; }
    float inv = 1.f / sum;
    float sv = 0.f;
#pragma unroll
    for (int l = 0; l < NL; ++l) sv = fmaf(sc[l] * inv, hd[l][k], sv);

    float p = sv * predw[k];
#pragma unroll
    for (int off = 32; off >= 1; off >>= 1) p += __shfl_xor(p, off);
    if (k == 0) {
      float x = p + predb[0];
      out[s] = (x >= 0.f) ? x : 0.01f * x;
    }
  }
}

// ---------------------------------------------------------------------------
extern "C" void kernel_launch(void* const* d_in, const int* in_sizes, int n_in,
                              void* d_out, int out_size, void* d_ws, size_t ws_size,
                              hipStream_t stream) {
  (void)in_sizes; (void)n_in; (void)out_size; (void)ws_size;

  const float* text    = (const float*)d_in[0];
  const float* time_in = (const float*)d_in[1];
  const float* Wdw     = (const float*)d_in[2];
  const float* Wdb     = (const float*)d_in[3];
  const float* Wallw   = (const float*)d_in[4];
  const float* Wallb   = (const float*)d_in[5];
  const float* Uallw   = (const float*)d_in[6];
  const float* Uallb   = (const float*)d_in[7];
  const float* tW1w    = (const float*)d_in[8];
  const float* tW1b    = (const float*)d_in[9];
  const float* tW2w    = (const float*)d_in[10];
  const float* tW2b    = (const float*)d_in[11];
  const float* tVw     = (const float*)d_in[12];
  const float* tVb     = (const float*)d_in[13];
  const float* ihw     = (const float*)d_in[14];
  const float* ihb     = (const float*)d_in[15];
  const float* hhb     = (const float*)d_in[16];
  const float* dW1w    = (const float*)d_in[17];
  const float* dW1b    = (const float*)d_in[18];
  const float* dW2w    = (const float*)d_in[19];
  const float* dW2b    = (const float*)d_in[20];
  const float* dVw     = (const float*)d_in[21];
  const float* dVb     = (const float*)d_in[22];
  const float* predw   = (const float*)d_in[23];
  const float* predb   = (const float*)d_in[24];

  float* ws      = (float*)d_ws;
  float* u       = ws;                              // S*300*256 = 6,758,400
  float* full    = u + (size_t)NS * NM * NG;        // S*L*T*H   = 1,689,600
  float* day_vec = full + (size_t)NS * NL * NT * NH;// S*L*H     =    56,320

  gemm_u_kernel<<<NS * 20, 256, 0, stream>>>(text, Uallw, Uallb, u);
  time_lstm_kernel<<<NS * NL, 320, 0, stream>>>(u, time_in, Wdw, Wdb,
                                                Wallw, Wallb, full);
  text_attn_kernel<<<NS * NL, 64, 0, stream>>>(full, tW1w, tW1b, tW2w, tW2b,
                                               tVw, tVb, day_vec);
  day_head_kernel<<<NS, 256, 0, stream>>>(day_vec, ihw, ihb, hhb,
                                          dW1w, dW1b, dW2w, dW2b, dVw, dVb,
                                          predw, predb, (float*)d_out);
}

// Round 3
// 197.300 us; speedup vs baseline: 2.2116x; 1.4675x over previous
//
#include <hip/hip_runtime.h>
#include <cmath>

#define NS 88
#define NL 10
#define NT 30
#define NE 768
#define NH 64
#define NG 256   // 4*H
#define NM 300   // L*T
#define MPAD 320 // M padded to 5*64

typedef _Float16 half_t;
typedef __attribute__((ext_vector_type(8))) _Float16 half8;
typedef __attribute__((ext_vector_type(4))) _Float16 half4v;
typedef __attribute__((ext_vector_type(4))) float f32x4;

__device__ inline void gload_lds16(const void* g, void* l) {
  __builtin_amdgcn_global_load_lds(
      (const __attribute__((address_space(1))) unsigned int*)g,
      (__attribute__((address_space(3))) unsigned int*)l, 16, 0, 0);
}

// ---------------------------------------------------------------------------
// convA: text fp32 [S,300,768] -> fp16 [S,320,768], rows 300..319 zeroed.
// ---------------------------------------------------------------------------
__global__ __launch_bounds__(256) void convA_kernel(
    const float* __restrict__ in, half_t* __restrict__ out)
{
  size_t i8 = ((size_t)blockIdx.x * 256 + threadIdx.x) * 8;  // 8 elems/thread
  int s  = (int)(i8 / (MPAD * NE));
  int rm = (int)(i8 % (MPAD * NE));
  int m  = rm / NE;
  int k  = rm % NE;
  half8 o;
  if (m < NM) {
    const float* p = in + ((size_t)s * NM + m) * NE + k;
    float4 x = *(const float4*)p;
    float4 y = *(const float4*)(p + 4);
    o[0] = (half_t)x.x; o[1] = (half_t)x.y; o[2] = (half_t)x.z; o[3] = (half_t)x.w;
    o[4] = (half_t)y.x; o[5] = (half_t)y.y; o[6] = (half_t)y.z; o[7] = (half_t)y.w;
  } else {
#pragma unroll
    for (int j = 0; j < 8; ++j) o[j] = (half_t)0.f;
  }
  *(half8*)(out + i8) = o;
}

// ---------------------------------------------------------------------------
// convB: Uall_w fp32 [S,768,256] -> fp16 transposed [S,256,768] (n-major,
// k contiguous). LDS 32x32 tile transpose. Grid: S * 24 * 8 blocks.
// ---------------------------------------------------------------------------
__global__ __launch_bounds__(256) void convB_kernel(
    const float* __restrict__ in, half_t* __restrict__ out)
{
  __shared__ float tile[32][36];
  int b  = blockIdx.x;
  int s  = b / 192;
  int r  = b % 192;
  int kt = r / 8;
  int nt = r % 8;
  int t  = threadIdx.x;

  int kk  = t >> 3;
  int nn4 = (t & 7) * 4;
  float4 v = *(const float4*)(in + ((size_t)s * NE + kt * 32 + kk) * NG + nt * 32 + nn4);
  tile[kk][nn4 + 0] = v.x; tile[kk][nn4 + 1] = v.y;
  tile[kk][nn4 + 2] = v.z; tile[kk][nn4 + 3] = v.w;
  __syncthreads();

  int nn = t >> 3;
  int kq = (t & 7) * 4;
  half4v o;
#pragma unroll
  for (int j = 0; j < 4; ++j) o[j] = (half_t)tile[kq + j][nn];
  *(half4v*)(out + ((size_t)s * NG + nt * 32 + nn) * NE + kt * 32 + kq) = o;
}

// ---------------------------------------------------------------------------
// gemm_mfma: U[s,m,n] = A[s,m,:] . B[s,n,:] + bias[s,n]
// A fp16 [S,320,768] (m-major, k contig), B fp16 [S,256,768] (n-major, k
// contig). Block tile 64m x 128n, 4 waves (2m x 2n), BK=64, 12 K-steps.
// global_load_lds(16B) staging with source-side XOR swizzle; swizzled
// ds_read_b128 fragment loads; mfma_f32_16x16x32_f16.
// ---------------------------------------------------------------------------
__global__ __launch_bounds__(256) void gemm_mfma_kernel(
    const half_t* __restrict__ Af16,
    const half_t* __restrict__ Bf16,
    const float* __restrict__ bias,   // [S,256]
    float* __restrict__ U)            // [S,300,256]
{
  __shared__ uint4 smem4[1536];       // 24 KiB: A 8K @0, B 16K @8192
  char* smem = (char*)smem4;

  int b   = blockIdx.x;
  int swz = (b & 7) * 110 + (b >> 3);   // 880 = 8*110, bijective XCD swizzle
  int s   = swz / 10;
  int rr_ = swz % 10;
  int m0  = (rr_ >> 1) * 64;
  int n0  = (rr_ & 1) * 128;

  int tid = threadIdx.x;
  int w = tid >> 6, l = tid & 63;
  int wm = w >> 1, wn = w & 1;
  int lr = l & 15, lk = l >> 4;       // fragment row/col, k-group

  const half_t* Ab = Af16 + ((size_t)s * MPAD + m0) * NE;
  const half_t* Bb = Bf16 + ((size_t)s * NG + n0) * NE;

  f32x4 acc[2][4];
#pragma unroll
  for (int i = 0; i < 2; ++i)
#pragma unroll
    for (int j = 0; j < 4; ++j) acc[i][j] = (f32x4){0.f, 0.f, 0.f, 0.f};

  for (int step = 0; step < 12; ++step) {
    int k0 = step * 64;
    // stage A: 64 rows x 64 k fp16 = 8KB (2 calls), linear LDS dest,
    // inverse-swizzled global source (chunk c -> c ^ (row&7)).
#pragma unroll
    for (int j = 0; j < 2; ++j) {
      int ci  = j * 256 + tid;
      int row = ci >> 3;
      int c   = (ci & 7) ^ (row & 7);
      gload_lds16(Ab + (size_t)row * NE + k0 + c * 8,
                  smem + j * 4096 + w * 1024);
    }
    // stage B: 128 rows x 64 k = 16KB (4 calls)
#pragma unroll
    for (int j = 0; j < 4; ++j) {
      int ci  = j * 256 + tid;
      int row = ci >> 3;
      int c   = (ci & 7) ^ (row & 7);
      gload_lds16(Bb + (size_t)row * NE + k0 + c * 8,
                  smem + 8192 + j * 4096 + w * 1024);
    }
    __syncthreads();   // drains vmcnt -> staged data visible

#pragma unroll
    for (int kk = 0; kk < 2; ++kk) {
      half8 af[2], bf[4];
#pragma unroll
      for (int fm = 0; fm < 2; ++fm) {
        int rw = wm * 32 + fm * 16 + lr;
        int cc = (kk * 4 + lk) ^ (rw & 7);
        af[fm] = *(const half8*)(smem + rw * 128 + cc * 16);
      }
#pragma unroll
      for (int fn = 0; fn < 4; ++fn) {
        int rw = wn * 64 + fn * 16 + lr;
        int cc = (kk * 4 + lk) ^ (rw & 7);
        bf[fn] = *(const half8*)(smem + 8192 + rw * 128 + cc * 16);
      }
#pragma unroll
      for (int fm = 0; fm < 2; ++fm)
#pragma unroll
        for (int fn = 0; fn < 4; ++fn)
          acc[fm][fn] = __builtin_amdgcn_mfma_f32_16x16x32_f16(
              af[fm], bf[fn], acc[fm][fn], 0, 0, 0);
    }
    __syncthreads();   // all reads done before next stage overwrites
  }

  // epilogue: D row = lk*4 + e, col = lr (m89-verified layout); add bias
#pragma unroll
  for (int fn = 0; fn < 4; ++fn) {
    int col = n0 + wn * 64 + fn * 16 + lr;
    float bv = bias[(size_t)s * NG + col];
#pragma unroll
    for (int fm = 0; fm < 2; ++fm) {
      int mbase = m0 + wm * 32 + fm * 16 + lk * 4;
#pragma unroll
      for (int e = 0; e < 4; ++e) {
        int m = mbase + e;
        if (m < NM)
          U[((size_t)s * NM + m) * NG + col] = acc[fm][fn][e] + bv;
      }
    }
  }
}

// ---------------------------------------------------------------------------
// TimeLSTM scan over T. One block per (stock, day): 880 x 320 threads.
// ---------------------------------------------------------------------------
__global__ __launch_bounds__(320) void time_lstm_kernel(
    const float* __restrict__ u,       // [S, L*T, 256]
    const float* __restrict__ time_in, // [S, L, T]
    const float* __restrict__ Wdw,     // [S, H, H]
    const float* __restrict__ Wdb,     // [S, H]
    const float* __restrict__ Wallw,   // [S, H, 4H]
    const float* __restrict__ Wallb,   // [S, 4H]
    float* __restrict__ full)          // [S, L, T, H]
{
  int bid = blockIdx.x;                // s*NL + l
  int s = bid / NL;
  int g = threadIdx.x;                 // 0..319
  bool is_gate = (g < NG);

  float wcol[NH];
  float wbias;
  if (is_gate) {
#pragma unroll
    for (int k = 0; k < NH; ++k)
      wcol[k] = Wallw[((size_t)s * NH + k) * NG + g];
    wbias = Wallb[(size_t)s * NG + g];
  } else {
    int j = g - NG;
#pragma unroll
    for (int k = 0; k < NH; ++k)
      wcol[k] = Wdw[((size_t)s * NH + k) * NH + j];
    wbias = Wdb[(size_t)s * NH + j];
  }

  __shared__ float h_s[NH];
  __shared__ float c_s[NH];
  __shared__ float cadj_s[NH];
  __shared__ float gates_s[NG];
  __shared__ float ts_s[NT];

  const float* u_base    = u + (size_t)bid * NT * NG;
  float*       full_base = full + (size_t)bid * NT * NH;

  if (g < NH) { h_s[g] = 0.f; c_s[g] = 0.f; }
  if (g < NT) ts_s[g] = time_in[(size_t)bid * NT + g];

  float u_next = is_gate ? u_base[g] : 0.f;   // prefetch t=0
  __syncthreads();

  for (int t = 0; t < NT; ++t) {
    float u_cur = u_next;
    if (is_gate && t + 1 < NT) u_next = u_base[(size_t)(t + 1) * NG + g];

    const float4* src4 = (const float4*)(is_gate ? h_s : c_s);
    float a0 = 0.f, a1 = 0.f, a2 = 0.f, a3 = 0.f;
#pragma unroll
    for (int k4 = 0; k4 < NH / 4; ++k4) {
      float4 v = src4[k4];
      a0 = fmaf(v.x, wcol[4 * k4 + 0], a0);
      a1 = fmaf(v.y, wcol[4 * k4 + 1], a1);
      a2 = fmaf(v.z, wcol[4 * k4 + 2], a2);
      a3 = fmaf(v.w, wcol[4 * k4 + 3], a3);
    }
    float dot = ((a0 + a1) + (a2 + a3)) + wbias;

    if (is_gate) {
      float acc = dot + u_cur;
      gates_s[g] = 1.f / (1.f + expf(-acc));
    } else {
      int j = g - NG;
      float cs1 = tanhf(dot);
      cadj_s[j] = c_s[j] + cs1 * (ts_s[t] - 1.f);
    }
    __syncthreads();

    if (g < NH) {                                   // f,i,o,g slice order
      float f  = gates_s[g];
      float ii = gates_s[NH + g];
      float o  = gates_s[2 * NH + g];
      float gg = gates_s[3 * NH + g];
      float cn = fmaf(f, cadj_s[g], ii * gg);
      c_s[g] = cn;
      float hn = o * tanhf(cn);
      h_s[g] = hn;
      full_base[(size_t)t * NH + g] = hn;
    }
    __syncthreads();
  }
}

// ---------------------------------------------------------------------------
// text attention over T. One block (64 thr = 1 wave) per (s,l).
// ---------------------------------------------------------------------------
__global__ __launch_bounds__(64) void text_attn_kernel(
    const float* __restrict__ full,   // [S, L, T, H]
    const float* __restrict__ tW1w, const float* __restrict__ tW1b,
    const float* __restrict__ tW2w, const float* __restrict__ tW2b,
    const float* __restrict__ tVw,  const float* __restrict__ tVb,
    float* __restrict__ day_vec)      // [S, L, H]
{
  int bid = blockIdx.x;            // s*L + l
  int s = bid / NL;
  int k = threadIdx.x;             // 0..63

  __shared__ float fl[NT][NH];
  const float* fp = full + (size_t)bid * NT * NH;
  for (int i = k; i < NT * NH; i += 64) ((float*)fl)[i] = fp[i];

  float tw2[NH];
#pragma unroll
  for (int h = 0; h < NH; ++h)
    tw2[h] = tW2w[((size_t)s * NH + h) * NH + k];
  __syncthreads();

  float a1 = tW1b[(size_t)s * NH + k];
#pragma unroll
  for (int h = 0; h < NH; ++h)
    a1 = fmaf(fl[NT-1][h], tW1w[((size_t)s * NH + h) * NH + k], a1);

  float b2k = tW2b[(size_t)s * NH + k];
  float tv  = tVw[(size_t)s * NH + k];
  float tvb = tVb[s];

  float score[NT];
#pragma unroll
  for (int t = 0; t < NT; ++t) {
    float a2 = b2k;
#pragma unroll
    for (int h = 0; h < NH; ++h) a2 = fmaf(fl[t][h], tw2[h], a2);
    float v = tanhf(a1 + a2) * tv;
#pragma unroll
    for (int off = 32; off >= 1; off >>= 1) v += __shfl_xor(v, off);
    score[t] = v + tvb;
  }
  float mx = score[0];
#pragma unroll
  for (int t = 1; t < NT; ++t) mx = fmaxf(mx, score[t]);
  float sum = 0.f;
#pragma unroll
  for (int t = 0; t < NT; ++t) { score[t] = expf(score[t] - mx); sum += score[t]; }
  float inv = 1.f / sum;
  float dv = 0.f;
#pragma unroll
  for (int t = 0; t < NT; ++t) dv = fmaf(score[t] * inv, fl[t][k], dv);
  day_vec[(size_t)bid * NH + k] = dv;
}

// ---------------------------------------------------------------------------
// day LSTM + day attention + pred head. One block per stock.
// ---------------------------------------------------------------------------
__global__ __launch_bounds__(256) void day_head_kernel(
    const float* __restrict__ day_vec, // [S, L, H]
    const float* __restrict__ ihw, const float* __restrict__ ihb,
    const float* __restrict__ hhb,
    const float* __restrict__ dW1w, const float* __restrict__ dW1b,
    const float* __restrict__ dW2w, const float* __restrict__ dW2b,
    const float* __restrict__ dVw,  const float* __restrict__ dVb,
    const float* __restrict__ predw, const float* __restrict__ predb,
    float* __restrict__ out)           // [S]
{
  int s = blockIdx.x;
  int g = threadIdx.x;
  int j = g & 63;
  int q = g >> 6;

  __shared__ float dv_s[NL][NH];
  __shared__ float gl[NL][NG];
  __shared__ float hd[NL][NH];

  for (int i = g; i < NL * NH; i += 256)
    ((float*)dv_s)[i] = day_vec[(size_t)s * NL * NH + i];
  __syncthreads();

  float ihcol[NH];
#pragma unroll
  for (int k = 0; k < NH; ++k)
    ihcol[k] = ihw[((size_t)s * NH + k) * NG + g];
  float bias = ihb[(size_t)s * NG + g] + hhb[(size_t)s * NG + g];

  bool is_gpart = (g >= 128 && g < 192);
  for (int l = 0; l < NL; ++l) {
    float acc = bias;
#pragma unroll
    for (int k = 0; k < NH; ++k) acc = fmaf(dv_s[l][k], ihcol[k], acc);
    gl[l][g] = is_gpart ? tanhf(acc) : 1.f / (1.f + expf(-acc));
  }
  __syncthreads();
  for (int l = q; l < NL; l += 4) {
    float cd = gl[l][j] * gl[l][128 + j];       // sig(i)*tanh(g)
    hd[l][j] = gl[l][192 + j] * tanhf(cd);      // sig(o)*tanh(c)
  }
  __syncthreads();

  if (g < 64) {
    int k = g;
    float dw1c[NH], dw2c[NH];
#pragma unroll
    for (int h = 0; h < NH; ++h) {
      dw1c[h] = dW1w[((size_t)s * NH + h) * NH + k];
      dw2c[h] = dW2w[((size_t)s * NH + h) * NH + k];
    }
    float b1 = dW1b[(size_t)s * NH + k];
    float b2 = dW2b[(size_t)s * NH + k];
    float dv = dVw[(size_t)s * NH + k];
    float dvb = dVb[s];

    float sc[NL];
#pragma unroll
    for (int l = 0; l < NL; ++l) {
      float x1 = b1, x2 = b2;
#pragma unroll
      for (int h = 0; h < NH; ++h) {
        x1 = fmaf(hd[l][h], dw1c[h], x1);
        x2 = fmaf(hd[l][h], dw2c[h], x2);
      }
      float v = tanhf(x1 + x2) * dv;
#pragma unroll
      for (int off = 32; off >= 1; off >>= 1) v += __shfl_xor(v, off);
      sc[l] = v + dvb;
    }
    float mx = sc[0];
#pragma unroll
    for (int l = 1; l < NL; ++l) mx = fmaxf(mx, sc[l]);
    float sum = 0.f;
#pragma unroll
    for (int l = 0; l < NL; ++l) { sc[l] = expf(sc[l] - mx); sum += sc[l]; }
    float inv = 1.f / sum;
    float sv = 0.f;
#pragma unroll
    for (int l = 0; l < NL; ++l) sv = fmaf(sc[l] * inv, hd[l][k], sv);

    float p = sv * predw[k];
#pragma unroll
    for (int off = 32; off >= 1; off >>= 1) p += __shfl_xor(p, off);
    if (k == 0) {
      float x = p + predb[0];
      out[s] = (x >= 0.f) ? x : 0.01f * x;
    }
  }
}

// ---------------------------------------------------------------------------
extern "C" void kernel_launch(void* const* d_in, const int* in_sizes, int n_in,
                              void* d_out, int out_size, void* d_ws, size_t ws_size,
                              hipStream_t stream) {
  (void)in_sizes; (void)n_in; (void)out_size; (void)ws_size;

  const float* text    = (const float*)d_in[0];
  const float* time_in = (const float*)d_in[1];
  const float* Wdw     = (const float*)d_in[2];
  const float* Wdb     = (const float*)d_in[3];
  const float* Wallw   = (const float*)d_in[4];
  const float* Wallb   = (const float*)d_in[5];
  const float* Uallw   = (const float*)d_in[6];
  const float* Uallb   = (const float*)d_in[7];
  const float* tW1w    = (const float*)d_in[8];
  const float* tW1b    = (const float*)d_in[9];
  const float* tW2w    = (const float*)d_in[10];
  const float* tW2b    = (const float*)d_in[11];
  const float* tVw     = (const float*)d_in[12];
  const float* tVb     = (const float*)d_in[13];
  const float* ihw     = (const float*)d_in[14];
  const float* ihb     = (const float*)d_in[15];
  const float* hhb     = (const float*)d_in[16];
  const float* dW1w    = (const float*)d_in[17];
  const float* dW1b    = (const float*)d_in[18];
  const float* dW2w    = (const float*)d_in[19];
  const float* dW2b    = (const float*)d_in[20];
  const float* dVw     = (const float*)d_in[21];
  const float* dVb     = (const float*)d_in[22];
  const float* predw   = (const float*)d_in[23];
  const float* predb   = (const float*)d_in[24];

  float* ws      = (float*)d_ws;
  float* u       = ws;                                // S*300*256 f32
  float* full    = u + (size_t)NS * NM * NG;          // S*L*T*H  f32
  float* day_vec = full + (size_t)NS * NL * NT * NH;  // S*L*H    f32
  half_t* Af16   = (half_t*)(day_vec + (size_t)NS * NL * NH); // S*320*768 f16
  half_t* Bf16   = Af16 + (size_t)NS * MPAD * NE;             // S*256*768 f16
  // total ws: ~111 MB

  convA_kernel<<<(NS * MPAD * NE) / (8 * 256), 256, 0, stream>>>(text, Af16);
  convB_kernel<<<NS * 192, 256, 0, stream>>>(Uallw, Bf16);
  gemm_mfma_kernel<<<NS * 10, 256, 0, stream>>>(Af16, Bf16, Uallb, u);
  time_lstm_kernel<<<NS * NL, 320, 0, stream>>>(u, time_in, Wdw, Wdb,
                                                Wallw, Wallb, full);
  text_attn_kernel<<<NS * NL, 64, 0, stream>>>(full, tW1w, tW1b, tW2w, tW2b,
                                               tVw, tVb, day_vec);
  day_head_kernel<<<NS, 256, 0, stream>>>(day_vec, ihw, ihb, hhb,
                                          dW1w, dW1b, dW2w, dW2b, dVw, dVb,
                                          predw, predb, (float*)d_out);
}

// Round 4
// 190.046 us; speedup vs baseline: 2.2960x; 1.0382x over previous
//
#include <hip/hip_runtime.h>
#include <cmath>

#define NS 88
#define NL 10
#define NT 30
#define NE 768
#define NH 64
#define NG 256   // 4*H
#define NM 300   // L*T
#define MPAD 320 // M padded to 5*64

typedef _Float16 half_t;
typedef __attribute__((ext_vector_type(8))) _Float16 half8;
typedef __attribute__((ext_vector_type(4))) _Float16 half4v;
typedef __attribute__((ext_vector_type(4))) float f32x4;

__device__ inline void gload_lds16(const void* g, void* l) {
  __builtin_amdgcn_global_load_lds(
      (const __attribute__((address_space(1))) unsigned int*)g,
      (__attribute__((address_space(3))) unsigned int*)l, 16, 0, 0);
}

// fast sigmoid/tanh: v_exp_f32 + v_rcp_f32 (~1 ulp each; error budget 12x)
__device__ inline float fsigmoid(float x) {
  return __builtin_amdgcn_rcpf(1.f + __expf(-x));
}
__device__ inline float ftanh(float x) {
  float e = __expf(2.f * x);
  return 1.f - 2.f * __builtin_amdgcn_rcpf(e + 1.f);
}

// ---------------------------------------------------------------------------
// convA: text fp32 [S,300,768] -> fp16 [S,320,768], rows 300..319 zeroed.
// ---------------------------------------------------------------------------
__global__ __launch_bounds__(256) void convA_kernel(
    const float* __restrict__ in, half_t* __restrict__ out)
{
  size_t i8 = ((size_t)blockIdx.x * 256 + threadIdx.x) * 8;  // 8 elems/thread
  int s  = (int)(i8 / (MPAD * NE));
  int rm = (int)(i8 % (MPAD * NE));
  int m  = rm / NE;
  int k  = rm % NE;
  half8 o;
  if (m < NM) {
    const float* p = in + ((size_t)s * NM + m) * NE + k;
    float4 x = *(const float4*)p;
    float4 y = *(const float4*)(p + 4);
    o[0] = (half_t)x.x; o[1] = (half_t)x.y; o[2] = (half_t)x.z; o[3] = (half_t)x.w;
    o[4] = (half_t)y.x; o[5] = (half_t)y.y; o[6] = (half_t)y.z; o[7] = (half_t)y.w;
  } else {
#pragma unroll
    for (int j = 0; j < 8; ++j) o[j] = (half_t)0.f;
  }
  *(half8*)(out + i8) = o;
}

// ---------------------------------------------------------------------------
// convB: Uall_w fp32 [S,768,256] -> fp16 transposed [S,256,768] (n-major,
// k contiguous). LDS 32x32 tile transpose. Grid: S * 24 * 8 blocks.
// ---------------------------------------------------------------------------
__global__ __launch_bounds__(256) void convB_kernel(
    const float* __restrict__ in, half_t* __restrict__ out)
{
  __shared__ float tile[32][36];
  int b  = blockIdx.x;
  int s  = b / 192;
  int r  = b % 192;
  int kt = r / 8;
  int nt = r % 8;
  int t  = threadIdx.x;

  int kk  = t >> 3;
  int nn4 = (t & 7) * 4;
  float4 v = *(const float4*)(in + ((size_t)s * NE + kt * 32 + kk) * NG + nt * 32 + nn4);
  tile[kk][nn4 + 0] = v.x; tile[kk][nn4 + 1] = v.y;
  tile[kk][nn4 + 2] = v.z; tile[kk][nn4 + 3] = v.w;
  __syncthreads();

  int nn = t >> 3;
  int kq = (t & 7) * 4;
  half4v o;
#pragma unroll
  for (int j = 0; j < 4; ++j) o[j] = (half_t)tile[kq + j][nn];
  *(half4v*)(out + ((size_t)s * NG + nt * 32 + nn) * NE + kt * 32 + kq) = o;
}

// ---------------------------------------------------------------------------
// gemm_mfma: U[s,m,n] = A[s,m,:] . B[s,n,:] + bias[s,n]
// 64m x 128n block tile, 4 waves (2m x 2n), BK=64, 12 K-steps.
// global_load_lds(16B) staging, source-side XOR swizzle, mfma 16x16x32 f16.
// ---------------------------------------------------------------------------
__global__ __launch_bounds__(256) void gemm_mfma_kernel(
    const half_t* __restrict__ Af16,
    const half_t* __restrict__ Bf16,
    const float* __restrict__ bias,   // [S,256]
    float* __restrict__ U)            // [S,300,256]
{
  __shared__ uint4 smem4[1536];       // 24 KiB: A 8K @0, B 16K @8192
  char* smem = (char*)smem4;

  int b   = blockIdx.x;
  int swz = (b & 7) * 110 + (b >> 3);   // 880 = 8*110, bijective XCD swizzle
  int s   = swz / 10;
  int rr_ = swz % 10;
  int m0  = (rr_ >> 1) * 64;
  int n0  = (rr_ & 1) * 128;

  int tid = threadIdx.x;
  int w = tid >> 6, l = tid & 63;
  int wm = w >> 1, wn = w & 1;
  int lr = l & 15, lk = l >> 4;       // fragment row, k-group

  const half_t* Ab = Af16 + ((size_t)s * MPAD + m0) * NE;
  const half_t* Bb = Bf16 + ((size_t)s * NG + n0) * NE;

  f32x4 acc[2][4];
#pragma unroll
  for (int i = 0; i < 2; ++i)
#pragma unroll
    for (int j = 0; j < 4; ++j) acc[i][j] = (f32x4){0.f, 0.f, 0.f, 0.f};

  for (int step = 0; step < 12; ++step) {
    int k0 = step * 64;
#pragma unroll
    for (int j = 0; j < 2; ++j) {       // stage A: 8KB
      int ci  = j * 256 + tid;
      int row = ci >> 3;
      int c   = (ci & 7) ^ (row & 7);
      gload_lds16(Ab + (size_t)row * NE + k0 + c * 8,
                  smem + j * 4096 + w * 1024);
    }
#pragma unroll
    for (int j = 0; j < 4; ++j) {       // stage B: 16KB
      int ci  = j * 256 + tid;
      int row = ci >> 3;
      int c   = (ci & 7) ^ (row & 7);
      gload_lds16(Bb + (size_t)row * NE + k0 + c * 8,
                  smem + 8192 + j * 4096 + w * 1024);
    }
    __syncthreads();

#pragma unroll
    for (int kk = 0; kk < 2; ++kk) {
      half8 af[2], bf[4];
#pragma unroll
      for (int fm = 0; fm < 2; ++fm) {
        int rw = wm * 32 + fm * 16 + lr;
        int cc = (kk * 4 + lk) ^ (rw & 7);
        af[fm] = *(const half8*)(smem + rw * 128 + cc * 16);
      }
#pragma unroll
      for (int fn = 0; fn < 4; ++fn) {
        int rw = wn * 64 + fn * 16 + lr;
        int cc = (kk * 4 + lk) ^ (rw & 7);
        bf[fn] = *(const half8*)(smem + 8192 + rw * 128 + cc * 16);
      }
#pragma unroll
      for (int fm = 0; fm < 2; ++fm)
#pragma unroll
        for (int fn = 0; fn < 4; ++fn)
          acc[fm][fn] = __builtin_amdgcn_mfma_f32_16x16x32_f16(
              af[fm], bf[fn], acc[fm][fn], 0, 0, 0);
    }
    __syncthreads();
  }

#pragma unroll
  for (int fn = 0; fn < 4; ++fn) {
    int col = n0 + wn * 64 + fn * 16 + lr;
    float bv = bias[(size_t)s * NG + col];
#pragma unroll
    for (int fm = 0; fm < 2; ++fm) {
      int mbase = m0 + wm * 32 + fm * 16 + lk * 4;
#pragma unroll
      for (int e = 0; e < 4; ++e) {
        int m = mbase + e;
        if (m < NM)
          U[((size_t)s * NM + m) * NG + col] = acc[fm][fn][e] + bv;
      }
    }
  }
}

// ---------------------------------------------------------------------------
// TimeLSTM scan over T. One block per (stock, day): 880 x 320 threads.
// VMEM-free main loop: u tile + ts preloaded to LDS, h history accumulated
// in LDS, written coalesced at the end. Barriers drain only lgkmcnt.
// ---------------------------------------------------------------------------
__global__ __launch_bounds__(320) void time_lstm_kernel(
    const float* __restrict__ u,       // [S, L*T, 256]
    const float* __restrict__ time_in, // [S, L, T]
    const float* __restrict__ Wdw,     // [S, H, H]
    const float* __restrict__ Wdb,     // [S, H]
    const float* __restrict__ Wallw,   // [S, H, 4H]
    const float* __restrict__ Wallb,   // [S, 4H]
    float* __restrict__ full)          // [S, L, T, H]
{
  int bid = blockIdx.x;                // s*NL + l
  int s = bid / NL;
  int g = threadIdx.x;                 // 0..319
  bool is_gate = (g < NG);

  __shared__ float u_s[NT][NG];        // 30 KiB
  __shared__ float hist[NT][NH];       // 7.5 KiB
  __shared__ float h_s[NH];
  __shared__ float c_s[NH];
  __shared__ float cadj_s[NH];
  __shared__ float gates_s[NG];
  __shared__ float ts_s[NT];

  // preload u tile: 1920 float4, 320 threads -> 6 each (coalesced)
  {
    const float4* src = (const float4*)(u + (size_t)bid * NT * NG);
    float4* dst = (float4*)&u_s[0][0];
#pragma unroll
    for (int i = 0; i < 6; ++i)
      dst[i * 320 + g] = src[i * 320 + g];
  }
  if (g < NT) ts_s[g] = time_in[(size_t)bid * NT + g];
  if (g < NH) { h_s[g] = 0.f; c_s[g] = 0.f; }

  // weight column in registers: Wall col g (gate threads) / Wd col g-256
  float wcol[NH];
  float wbias;
  if (is_gate) {
#pragma unroll
    for (int k = 0; k < NH; ++k)
      wcol[k] = Wallw[((size_t)s * NH + k) * NG + g];
    wbias = Wallb[(size_t)s * NG + g];
  } else {
    int j = g - NG;
#pragma unroll
    for (int k = 0; k < NH; ++k)
      wcol[k] = Wdw[((size_t)s * NH + k) * NH + j];
    wbias = Wdb[(size_t)s * NH + j];
  }
  __syncthreads();

  for (int t = 0; t < NT; ++t) {
    const float4* src4 = (const float4*)(is_gate ? h_s : c_s);
    float a0 = 0.f, a1 = 0.f, a2 = 0.f, a3 = 0.f;
#pragma unroll
    for (int k4 = 0; k4 < NH / 4; ++k4) {
      float4 v = src4[k4];
      a0 = fmaf(v.x, wcol[4 * k4 + 0], a0);
      a1 = fmaf(v.y, wcol[4 * k4 + 1], a1);
      a2 = fmaf(v.z, wcol[4 * k4 + 2], a2);
      a3 = fmaf(v.w, wcol[4 * k4 + 3], a3);
    }
    float dot = ((a0 + a1) + (a2 + a3)) + wbias;

    if (is_gate) {
      gates_s[g] = fsigmoid(dot + u_s[t][g]);
    } else {
      int j = g - NG;
      cadj_s[j] = c_s[j] + ftanh(dot) * (ts_s[t] - 1.f);
    }
    __syncthreads();

    if (g < NH) {                                   // f,i,o,g slice order
      float f  = gates_s[g];
      float ii = gates_s[NH + g];
      float o  = gates_s[2 * NH + g];
      float gg = gates_s[3 * NH + g];
      float cn = fmaf(f, cadj_s[g], ii * gg);
      c_s[g] = cn;
      float hn = o * ftanh(cn);
      h_s[g] = hn;
      hist[t][g] = hn;
    }
    __syncthreads();
  }

  // write full once, coalesced: 480 float4
  {
    const float4* src = (const float4*)&hist[0][0];
    float4* dst = (float4*)(full + (size_t)bid * NT * NH);
    for (int i = g; i < 480; i += 320) dst[i] = src[i];
  }
}

// ---------------------------------------------------------------------------
// text attention over T. One block (64 thr = 1 wave) per (s,l).
// ---------------------------------------------------------------------------
__global__ __launch_bounds__(64) void text_attn_kernel(
    const float* __restrict__ full,   // [S, L, T, H]
    const float* __restrict__ tW1w, const float* __restrict__ tW1b,
    const float* __restrict__ tW2w, const float* __restrict__ tW2b,
    const float* __restrict__ tVw,  const float* __restrict__ tVb,
    float* __restrict__ day_vec)      // [S, L, H]
{
  int bid = blockIdx.x;            // s*L + l
  int s = bid / NL;
  int k = threadIdx.x;             // 0..63

  __shared__ float fl[NT][NH];
  const float* fp = full + (size_t)bid * NT * NH;
  for (int i = k; i < NT * NH; i += 64) ((float*)fl)[i] = fp[i];

  float tw2[NH];
#pragma unroll
  for (int h = 0; h < NH; ++h)
    tw2[h] = tW2w[((size_t)s * NH + h) * NH + k];
  __syncthreads();

  float a1 = tW1b[(size_t)s * NH + k];
#pragma unroll
  for (int h = 0; h < NH; ++h)
    a1 = fmaf(fl[NT-1][h], tW1w[((size_t)s * NH + h) * NH + k], a1);

  float b2k = tW2b[(size_t)s * NH + k];
  float tv  = tVw[(size_t)s * NH + k];
  float tvb = tVb[s];

  float score[NT];
#pragma unroll
  for (int t = 0; t < NT; ++t) {
    float a2 = b2k;
#pragma unroll
    for (int h = 0; h < NH; ++h) a2 = fmaf(fl[t][h], tw2[h], a2);
    float v = ftanh(a1 + a2) * tv;
#pragma unroll
    for (int off = 32; off >= 1; off >>= 1) v += __shfl_xor(v, off);
    score[t] = v + tvb;
  }
  float mx = score[0];
#pragma unroll
  for (int t = 1; t < NT; ++t) mx = fmaxf(mx, score[t]);
  float sum = 0.f;
#pragma unroll
  for (int t = 0; t < NT; ++t) { score[t] = __expf(score[t] - mx); sum += score[t]; }
  float inv = __builtin_amdgcn_rcpf(sum);
  float dv = 0.f;
#pragma unroll
  for (int t = 0; t < NT; ++t) dv = fmaf(score[t] * inv, fl[t][k], dv);
  day_vec[(size_t)bid * NH + k] = dv;
}

// ---------------------------------------------------------------------------
// day LSTM + day attention + pred head. One block per stock.
// ---------------------------------------------------------------------------
__global__ __launch_bounds__(256) void day_head_kernel(
    const float* __restrict__ day_vec, // [S, L, H]
    const float* __restrict__ ihw, const float* __restrict__ ihb,
    const float* __restrict__ hhb,
    const float* __restrict__ dW1w, const float* __restrict__ dW1b,
    const float* __restrict__ dW2w, const float* __restrict__ dW2b,
    const float* __restrict__ dVw,  const float* __restrict__ dVb,
    const float* __restrict__ predw, const float* __restrict__ predb,
    float* __restrict__ out)           // [S]
{
  int s = blockIdx.x;
  int g = threadIdx.x;
  int j = g & 63;
  int q = g >> 6;

  __shared__ float dv_s[NL][NH];
  __shared__ float gl[NL][NG];
  __shared__ float hd[NL][NH];

  for (int i = g; i < NL * NH; i += 256)
    ((float*)dv_s)[i] = day_vec[(size_t)s * NL * NH + i];
  __syncthreads();

  float ihcol[NH];
#pragma unroll
  for (int k = 0; k < NH; ++k)
    ihcol[k] = ihw[((size_t)s * NH + k) * NG + g];
  float bias = ihb[(size_t)s * NG + g] + hhb[(size_t)s * NG + g];

  bool is_gpart = (g >= 128 && g < 192);
  for (int l = 0; l < NL; ++l) {
    float acc = bias;
#pragma unroll
    for (int k = 0; k < NH; ++k) acc = fmaf(dv_s[l][k], ihcol[k], acc);
    gl[l][g] = is_gpart ? ftanh(acc) : fsigmoid(acc);
  }
  __syncthreads();
  for (int l = q; l < NL; l += 4) {
    float cd = gl[l][j] * gl[l][128 + j];       // sig(i)*tanh(g)
    hd[l][j] = gl[l][192 + j] * ftanh(cd);      // sig(o)*tanh(c)
  }
  __syncthreads();

  if (g < 64) {
    int k = g;
    float dw1c[NH], dw2c[NH];
#pragma unroll
    for (int h = 0; h < NH; ++h) {
      dw1c[h] = dW1w[((size_t)s * NH + h) * NH + k];
      dw2c[h] = dW2w[((size_t)s * NH + h) * NH + k];
    }
    float b1 = dW1b[(size_t)s * NH + k];
    float b2 = dW2b[(size_t)s * NH + k];
    float dv = dVw[(size_t)s * NH + k];
    float dvb = dVb[s];

    float sc[NL];
#pragma unroll
    for (int l = 0; l < NL; ++l) {
      float x1 = b1, x2 = b2;
#pragma unroll
      for (int h = 0; h < NH; ++h) {
        x1 = fmaf(hd[l][h], dw1c[h], x1);
        x2 = fmaf(hd[l][h], dw2c[h], x2);
      }
      float v = ftanh(x1 + x2) * dv;
#pragma unroll
      for (int off = 32; off >= 1; off >>= 1) v += __shfl_xor(v, off);
      sc[l] = v + dvb;
    }
    float mx = sc[0];
#pragma unroll
    for (int l = 1; l < NL; ++l) mx = fmaxf(mx, sc[l]);
    float sum = 0.f;
#pragma unroll
    for (int l = 0; l < NL; ++l) { sc[l] = __expf(sc[l] - mx); sum += sc[l]; }
    float inv = __builtin_amdgcn_rcpf(sum);
    float sv = 0.f;
#pragma unroll
    for (int l = 0; l < NL; ++l) sv = fmaf(sc[l] * inv, hd[l][k], sv);

    float p = sv * predw[k];
#pragma unroll
    for (int off = 32; off >= 1; off >>= 1) p += __shfl_xor(p, off);
    if (k == 0) {
      float x = p + predb[0];
      out[s] = (x >= 0.f) ? x : 0.01f * x;
    }
  }
}

// ---------------------------------------------------------------------------
extern "C" void kernel_launch(void* const* d_in, const int* in_sizes, int n_in,
                              void* d_out, int out_size, void* d_ws, size_t ws_size,
                              hipStream_t stream) {
  (void)in_sizes; (void)n_in; (void)out_size; (void)ws_size;

  const float* text    = (const float*)d_in[0];
  const float* time_in = (const float*)d_in[1];
  const float* Wdw     = (const float*)d_in[2];
  const float* Wdb     = (const float*)d_in[3];
  const float* Wallw   = (const float*)d_in[4];
  const float* Wallb   = (const float*)d_in[5];
  const float* Uallw   = (const float*)d_in[6];
  const float* Uallb   = (const float*)d_in[7];
  const float* tW1w    = (const float*)d_in[8];
  const float* tW1b    = (const float*)d_in[9];
  const float* tW2w    = (const float*)d_in[10];
  const float* tW2b    = (const float*)d_in[11];
  const float* tVw     = (const float*)d_in[12];
  const float* tVb     = (const float*)d_in[13];
  const float* ihw     = (const float*)d_in[14];
  const float* ihb     = (const float*)d_in[15];
  const float* hhb     = (const float*)d_in[16];
  const float* dW1w    = (const float*)d_in[17];
  const float* dW1b    = (const float*)d_in[18];
  const float* dW2w    = (const float*)d_in[19];
  const float* dW2b    = (const float*)d_in[20];
  const float* dVw     = (const float*)d_in[21];
  const float* dVb     = (const float*)d_in[22];
  const float* predw   = (const float*)d_in[23];
  const float* predb   = (const float*)d_in[24];

  float* ws      = (float*)d_ws;
  float* u       = ws;                                // S*300*256 f32
  float* full    = u + (size_t)NS * NM * NG;          // S*L*T*H  f32
  float* day_vec = full + (size_t)NS * NL * NT * NH;  // S*L*H    f32
  half_t* Af16   = (half_t*)(day_vec + (size_t)NS * NL * NH); // S*320*768 f16
  half_t* Bf16   = Af16 + (size_t)NS * MPAD * NE;             // S*256*768 f16

  convA_kernel<<<(NS * MPAD * NE) / (8 * 256), 256, 0, stream>>>(text, Af16);
  convB_kernel<<<NS * 192, 256, 0, stream>>>(Uallw, Bf16);
  gemm_mfma_kernel<<<NS * 10, 256, 0, stream>>>(Af16, Bf16, Uallb, u);
  time_lstm_kernel<<<NS * NL, 320, 0, stream>>>(u, time_in, Wdw, Wdb,
                                                Wallw, Wallb, full);
  text_attn_kernel<<<NS * NL, 64, 0, stream>>>(full, tW1w, tW1b, tW2w, tW2b,
                                               tVw, tVb, day_vec);
  day_head_kernel<<<NS, 256, 0, stream>>>(day_vec, ihw, ihb, hhb,
                                          dW1w, dW1b, dW2w, dW2b, dVw, dVb,
                                          predw, predb, (float*)d_out);
}

// Round 6
// 138.310 us; speedup vs baseline: 3.1548x; 1.3741x over previous
//
#include <hip/hip_runtime.h>
#include <cmath>

#define NS 88
#define NL 10
#define NT 30
#define NE 768
#define NH 64
#define NG 256   // 4*H
#define NM 300   // L*T
#define MPAD 320 // M padded to 5*64

typedef _Float16 half_t;
typedef __attribute__((ext_vector_type(2))) _Float16 half2_t;
typedef __attribute__((ext_vector_type(8))) _Float16 half8;
typedef __attribute__((ext_vector_type(4))) _Float16 half4v;
typedef __attribute__((ext_vector_type(4))) float f32x4;

__device__ inline void gload_lds16(const void* g, void* l) {
  __builtin_amdgcn_global_load_lds(
      (const __attribute__((address_space(1))) unsigned int*)g,
      (__attribute__((address_space(3))) unsigned int*)l, 16, 0, 0);
}

// fast sigmoid/tanh: v_exp_f32 + v_rcp_f32
__device__ inline float fsigmoid(float x) {
  return __builtin_amdgcn_rcpf(1.f + __expf(-x));
}
__device__ inline float ftanh(float x) {
  float e = __expf(2.f * x);
  return 1.f - 2.f * __builtin_amdgcn_rcpf(e + 1.f);
}

#if __has_builtin(__builtin_amdgcn_fdot2)
__device__ inline float fdot2(half2_t a, half2_t b, float c) {
  return __builtin_amdgcn_fdot2(a, b, c, false);   // v_dot2_f32_f16
}
#else
__device__ inline float fdot2(half2_t a, half2_t b, float c) {
  return fmaf((float)a[1], (float)b[1], fmaf((float)a[0], (float)b[0], c));
}
#endif

__device__ inline half2_t mk_h2(float a, float b) {
  half2_t r; r[0] = (half_t)a; r[1] = (half_t)b; return r;
}

// ---------------------------------------------------------------------------
// convA: text fp32 [S,300,768] -> fp16 [S,320,768], rows 300..319 zeroed.
// ---------------------------------------------------------------------------
__global__ __launch_bounds__(256) void convA_kernel(
    const float* __restrict__ in, half_t* __restrict__ out)
{
  size_t i8 = ((size_t)blockIdx.x * 256 + threadIdx.x) * 8;  // 8 elems/thread
  int s  = (int)(i8 / (MPAD * NE));
  int rm = (int)(i8 % (MPAD * NE));
  int m  = rm / NE;
  int k  = rm % NE;
  half8 o;
  if (m < NM) {
    const float* p = in + ((size_t)s * NM + m) * NE + k;
    float4 x = *(const float4*)p;
    float4 y = *(const float4*)(p + 4);
    o[0] = (half_t)x.x; o[1] = (half_t)x.y; o[2] = (half_t)x.z; o[3] = (half_t)x.w;
    o[4] = (half_t)y.x; o[5] = (half_t)y.y; o[6] = (half_t)y.z; o[7] = (half_t)y.w;
  } else {
#pragma unroll
    for (int j = 0; j < 8; ++j) o[j] = (half_t)0.f;
  }
  *(half8*)(out + i8) = o;
}

// ---------------------------------------------------------------------------
// convB: Uall_w fp32 [S,768,256] -> fp16 transposed [S,256,768] (n-major,
// k contiguous). LDS 32x32 tile transpose. Grid: S * 24 * 8 blocks.
// ---------------------------------------------------------------------------
__global__ __launch_bounds__(256) void convB_kernel(
    const float* __restrict__ in, half_t* __restrict__ out)
{
  __shared__ float tile[32][36];
  int b  = blockIdx.x;
  int s  = b / 192;
  int r  = b % 192;
  int kt = r / 8;
  int nt = r % 8;
  int t  = threadIdx.x;

  int kk  = t >> 3;
  int nn4 = (t & 7) * 4;
  float4 v = *(const float4*)(in + ((size_t)s * NE + kt * 32 + kk) * NG + nt * 32 + nn4);
  tile[kk][nn4 + 0] = v.x; tile[kk][nn4 + 1] = v.y;
  tile[kk][nn4 + 2] = v.z; tile[kk][nn4 + 3] = v.w;
  __syncthreads();

  int nn = t >> 3;
  int kq = (t & 7) * 4;
  half4v o;
#pragma unroll
  for (int j = 0; j < 4; ++j) o[j] = (half_t)tile[kq + j][nn];
  *(half4v*)(out + ((size_t)s * NG + nt * 32 + nn) * NE + kt * 32 + kq) = o;
}

// ---------------------------------------------------------------------------
// gemm_mfma: U[s,m,n] = A[s,m,:] . B[s,n,:] + bias[s,n]
// 64m x 128n block tile, 4 waves (2m x 2n), BK=64, 12 K-steps.
// ---------------------------------------------------------------------------
__global__ __launch_bounds__(256) void gemm_mfma_kernel(
    const half_t* __restrict__ Af16,
    const half_t* __restrict__ Bf16,
    const float* __restrict__ bias,   // [S,256]
    float* __restrict__ U)            // [S,300,256]
{
  __shared__ uint4 smem4[1536];       // 24 KiB: A 8K @0, B 16K @8192
  char* smem = (char*)smem4;

  int b   = blockIdx.x;
  int swz = (b & 7) * 110 + (b >> 3);   // 880 = 8*110, bijective XCD swizzle
  int s   = swz / 10;
  int rr_ = swz % 10;
  int m0  = (rr_ >> 1) * 64;
  int n0  = (rr_ & 1) * 128;

  int tid = threadIdx.x;
  int w = tid >> 6, l = tid & 63;
  int wm = w >> 1, wn = w & 1;
  int lr = l & 15, lk = l >> 4;       // fragment row, k-group

  const half_t* Ab = Af16 + ((size_t)s * MPAD + m0) * NE;
  const half_t* Bb = Bf16 + ((size_t)s * NG + n0) * NE;

  f32x4 acc[2][4];
#pragma unroll
  for (int i = 0; i < 2; ++i)
#pragma unroll
    for (int j = 0; j < 4; ++j) acc[i][j] = (f32x4){0.f, 0.f, 0.f, 0.f};

  for (int step = 0; step < 12; ++step) {
    int k0 = step * 64;
#pragma unroll
    for (int j = 0; j < 2; ++j) {       // stage A: 8KB
      int ci  = j * 256 + tid;
      int row = ci >> 3;
      int c   = (ci & 7) ^ (row & 7);
      gload_lds16(Ab + (size_t)row * NE + k0 + c * 8,
                  smem + j * 4096 + w * 1024);
    }
#pragma unroll
    for (int j = 0; j < 4; ++j) {       // stage B: 16KB
      int ci  = j * 256 + tid;
      int row = ci >> 3;
      int c   = (ci & 7) ^ (row & 7);
      gload_lds16(Bb + (size_t)row * NE + k0 + c * 8,
                  smem + 8192 + j * 4096 + w * 1024);
    }
    __syncthreads();

#pragma unroll
    for (int kk = 0; kk < 2; ++kk) {
      half8 af[2], bf[4];
#pragma unroll
      for (int fm = 0; fm < 2; ++fm) {
        int rw = wm * 32 + fm * 16 + lr;
        int cc = (kk * 4 + lk) ^ (rw & 7);
        af[fm] = *(const half8*)(smem + rw * 128 + cc * 16);
      }
#pragma unroll
      for (int fn = 0; fn < 4; ++fn) {
        int rw = wn * 64 + fn * 16 + lr;
        int cc = (kk * 4 + lk) ^ (rw & 7);
        bf[fn] = *(const half8*)(smem + 8192 + rw * 128 + cc * 16);
      }
#pragma unroll
      for (int fm = 0; fm < 2; ++fm)
#pragma unroll
        for (int fn = 0; fn < 4; ++fn)
          acc[fm][fn] = __builtin_amdgcn_mfma_f32_16x16x32_f16(
              af[fm], bf[fn], acc[fm][fn], 0, 0, 0);
    }
    __syncthreads();
  }

#pragma unroll
  for (int fn = 0; fn < 4; ++fn) {
    int col = n0 + wn * 64 + fn * 16 + lr;
    float bv = bias[(size_t)s * NG + col];
#pragma unroll
    for (int fm = 0; fm < 2; ++fm) {
      int mbase = m0 + wm * 32 + fm * 16 + lk * 4;
#pragma unroll
      for (int e = 0; e < 4; ++e) {
        int m = mbase + e;
        if (m < NM)
          U[((size_t)s * NM + m) * NG + col] = acc[fm][fn][e] + bv;
      }
    }
  }
}

// ---------------------------------------------------------------------------
// TimeLSTM: ONE WAVE per (stock, day) chain — barrier-free.
// Lane j owns h[j], c[j]; holds Wall cols {j,64+j,128+j,192+j} + Wd col j as
// packed f16 pairs (160 VGPR); dots via v_dot2_f32_f16 (f32 accumulate).
// h/c replicated through LDS as f16; single-wave => ds-ordering only, no
// s_barrier. u tile staged to LDS once via global_load_lds with PER-LANE
// source address (lane j supplies bytes [16j,16j+16) of each 1KB row —
// this was R5's bug: uniform source replicated 16 bytes across the row).
// ---------------------------------------------------------------------------
__global__ __launch_bounds__(64) void time_lstm_kernel(
    const float* __restrict__ u,       // [S, L*T, 256]
    const float* __restrict__ time_in, // [S, L, T]
    const float* __restrict__ Wdw,     // [S, H, H]
    const float* __restrict__ Wdb,     // [S, H]
    const float* __restrict__ Wallw,   // [S, H, 4H]
    const float* __restrict__ Wallb,   // [S, 4H]
    float* __restrict__ full)          // [S, L, T, H]
{
  int bid = blockIdx.x;                // s*NL + l
  int s = bid / NL;
  int j = threadIdx.x;                 // 0..63

  __shared__ float   u_s[NT * NG];     // 30 KiB
  __shared__ float   ts_s[NT];
  __shared__ half2_t h2_s[NH / 2];     // h replicated, f16
  __shared__ half2_t c2_s[NH / 2];     // c replicated, f16

  // stage u tile: 30 rows x 1KB. Per-lane global source (j*4 floats = 16B),
  // uniform LDS base; HW writes lane data at base + lane*16.
  const float* u_base = u + (size_t)bid * NT * NG;
#pragma unroll
  for (int i = 0; i < NT; ++i)
    gload_lds16(u_base + i * NG + j * 4, (char*)u_s + i * 1024);

  if (j < NT) ts_s[j] = time_in[(size_t)bid * NT + j];
  ((half_t*)h2_s)[j] = (half_t)0.f;
  ((half_t*)c2_s)[j] = (half_t)0.f;

  // weights -> packed f16 pairs in VGPRs
  const float* Wa  = Wallw + (size_t)s * NH * NG;
  const float* Wdp = Wdw   + (size_t)s * NH * NH;
  half2_t wf[32], wi[32], wo[32], wg[32], wd[32];
#pragma unroll
  for (int k2 = 0; k2 < 32; ++k2) {
    wf[k2] = mk_h2(Wa[(2*k2) * NG + j],        Wa[(2*k2+1) * NG + j]);
    wi[k2] = mk_h2(Wa[(2*k2) * NG + 64 + j],   Wa[(2*k2+1) * NG + 64 + j]);
    wo[k2] = mk_h2(Wa[(2*k2) * NG + 128 + j],  Wa[(2*k2+1) * NG + 128 + j]);
    wg[k2] = mk_h2(Wa[(2*k2) * NG + 192 + j],  Wa[(2*k2+1) * NG + 192 + j]);
    wd[k2] = mk_h2(Wdp[(2*k2) * NH + j],       Wdp[(2*k2+1) * NH + j]);
  }
  float bf = Wallb[(size_t)s * NG + j];
  float bi = Wallb[(size_t)s * NG + 64 + j];
  float bo = Wallb[(size_t)s * NG + 128 + j];
  float bg = Wallb[(size_t)s * NG + 192 + j];
  float bd = Wdb[(size_t)s * NH + j];

  // drain global_load_lds before reading u_s (single wave: no barrier)
  asm volatile("s_waitcnt vmcnt(0)" ::: "memory");

  float c_my = 0.f;
  float* fb = full + (size_t)bid * NT * NH;

  for (int t = 0; t < NT; ++t) {
    float accf = bf + u_s[t * NG + j];
    float acci = bi + u_s[t * NG + 64 + j];
    float acco = bo + u_s[t * NG + 128 + j];
    float accg = bg + u_s[t * NG + 192 + j];
    float accd = bd;
#pragma unroll
    for (int k2 = 0; k2 < 32; ++k2) {
      half2_t hv = h2_s[k2];            // broadcast ds_read (vectorizes b128)
      half2_t cv = c2_s[k2];
      accf = fdot2(hv, wf[k2], accf);
      acci = fdot2(hv, wi[k2], acci);
      acco = fdot2(hv, wo[k2], acco);
      accg = fdot2(hv, wg[k2], accg);
      accd = fdot2(cv, wd[k2], accd);
    }
    float f  = fsigmoid(accf);          // reference: all-sigmoid gates
    float ii = fsigmoid(acci);
    float o  = fsigmoid(acco);
    float gg = fsigmoid(accg);
    float cadj = c_my + ftanh(accd) * (ts_s[t] - 1.f);
    float cn = fmaf(f, cadj, ii * gg);
    c_my = cn;
    float hn = o * ftanh(cn);
    ((half_t*)h2_s)[j] = (half_t)hn;    // lane-local b16 write; lgkmcnt orders
    ((half_t*)c2_s)[j] = (half_t)cn;
    fb[t * NH + j] = hn;                // fire-and-forget store
  }
}

// ---------------------------------------------------------------------------
// text attention over T. One block (64 thr = 1 wave) per (s,l).
// ---------------------------------------------------------------------------
__global__ __launch_bounds__(64) void text_attn_kernel(
    const float* __restrict__ full,   // [S, L, T, H]
    const float* __restrict__ tW1w, const float* __restrict__ tW1b,
    const float* __restrict__ tW2w, const float* __restrict__ tW2b,
    const float* __restrict__ tVw,  const float* __restrict__ tVb,
    float* __restrict__ day_vec)      // [S, L, H]
{
  int bid = blockIdx.x;            // s*L + l
  int s = bid / NL;
  int k = threadIdx.x;             // 0..63

  __shared__ float fl[NT][NH];
  const float* fp = full + (size_t)bid * NT * NH;
  for (int i = k; i < NT * NH; i += 64) ((float*)fl)[i] = fp[i];

  float tw2[NH];
#pragma unroll
  for (int h = 0; h < NH; ++h)
    tw2[h] = tW2w[((size_t)s * NH + h) * NH + k];
  __syncthreads();

  float a1 = tW1b[(size_t)s * NH + k];
#pragma unroll
  for (int h = 0; h < NH; ++h)
    a1 = fmaf(fl[NT-1][h], tW1w[((size_t)s * NH + h) * NH + k], a1);

  float b2k = tW2b[(size_t)s * NH + k];
  float tv  = tVw[(size_t)s * NH + k];
  float tvb = tVb[s];

  float score[NT];
#pragma unroll
  for (int t = 0; t < NT; ++t) {
    float a2 = b2k;
#pragma unroll
    for (int h = 0; h < NH; ++h) a2 = fmaf(fl[t][h], tw2[h], a2);
    float v = ftanh(a1 + a2) * tv;
#pragma unroll
    for (int off = 32; off >= 1; off >>= 1) v += __shfl_xor(v, off);
    score[t] = v + tvb;
  }
  float mx = score[0];
#pragma unroll
  for (int t = 1; t < NT; ++t) mx = fmaxf(mx, score[t]);
  float sum = 0.f;
#pragma unroll
  for (int t = 0; t < NT; ++t) { score[t] = __expf(score[t] - mx); sum += score[t]; }
  float inv = __builtin_amdgcn_rcpf(sum);
  float dv = 0.f;
#pragma unroll
  for (int t = 0; t < NT; ++t) dv = fmaf(score[t] * inv, fl[t][k], dv);
  day_vec[(size_t)bid * NH + k] = dv;
}

// ---------------------------------------------------------------------------
// day LSTM + day attention + pred head. One block per stock.
// ---------------------------------------------------------------------------
__global__ __launch_bounds__(256) void day_head_kernel(
    const float* __restrict__ day_vec, // [S, L, H]
    const float* __restrict__ ihw, const float* __restrict__ ihb,
    const float* __restrict__ hhb,
    const float* __restrict__ dW1w, const float* __restrict__ dW1b,
    const float* __restrict__ dW2w, const float* __restrict__ dW2b,
    const float* __restrict__ dVw,  const float* __restrict__ dVb,
    const float* __restrict__ predw, const float* __restrict__ predb,
    float* __restrict__ out)           // [S]
{
  int s = blockIdx.x;
  int g = threadIdx.x;
  int j = g & 63;
  int q = g >> 6;

  __shared__ float dv_s[NL][NH];
  __shared__ float gl[NL][NG];
  __shared__ float hd[NL][NH];

  for (int i = g; i < NL * NH; i += 256)
    ((float*)dv_s)[i] = day_vec[(size_t)s * NL * NH + i];
  __syncthreads();

  float ihcol[NH];
#pragma unroll
  for (int k = 0; k < NH; ++k)
    ihcol[k] = ihw[((size_t)s * NH + k) * NG + g];
  float bias = ihb[(size_t)s * NG + g] + hhb[(size_t)s * NG + g];

  bool is_gpart = (g >= 128 && g < 192);
  for (int l = 0; l < NL; ++l) {
    float acc = bias;
#pragma unroll
    for (int k = 0; k < NH; ++k) acc = fmaf(dv_s[l][k], ihcol[k], acc);
    gl[l][g] = is_gpart ? ftanh(acc) : fsigmoid(acc);
  }
  __syncthreads();
  for (int l = q; l < NL; l += 4) {
    float cd = gl[l][j] * gl[l][128 + j];       // sig(i)*tanh(g)
    hd[l][j] = gl[l][192 + j] * ftanh(cd);      // sig(o)*tanh(c)
  }
  __syncthreads();

  if (g < 64) {
    int k = g;
    float dw1c[NH], dw2c[NH];
#pragma unroll
    for (int h = 0; h < NH; ++h) {
      dw1c[h] = dW1w[((size_t)s * NH + h) * NH + k];
      dw2c[h] = dW2w[((size_t)s * NH + h) * NH + k];
    }
    float b1 = dW1b[(size_t)s * NH + k];
    float b2 = dW2b[(size_t)s * NH + k];
    float dv = dVw[(size_t)s * NH + k];
    float dvb = dVb[s];

    float sc[NL];
#pragma unroll
    for (int l = 0; l < NL; ++l) {
      float x1 = b1, x2 = b2;
#pragma unroll
      for (int h = 0; h < NH; ++h) {
        x1 = fmaf(hd[l][h], dw1c[h], x1);
        x2 = fmaf(hd[l][h], dw2c[h], x2);
      }
      float v = ftanh(x1 + x2) * dv;
#pragma unroll
      for (int off = 32; off >= 1; off >>= 1) v += __shfl_xor(v, off);
      sc[l] = v + dvb;
    }
    float mx = sc[0];
#pragma unroll
    for (int l = 1; l < NL; ++l) mx = fmaxf(mx, sc[l]);
    float sum = 0.f;
#pragma unroll
    for (int l = 0; l < NL; ++l) { sc[l] = __expf(sc[l] - mx); sum += sc[l]; }
    float inv = __builtin_amdgcn_rcpf(sum);
    float sv = 0.f;
#pragma unroll
    for (int l = 0; l < NL; ++l) sv = fmaf(sc[l] * inv, hd[l][k], sv);

    float p = sv * predw[k];
#pragma unroll
    for (int off = 32; off >= 1; off >>= 1) p += __shfl_xor(p, off);
    if (k == 0) {
      float x = p + predb[0];
      out[s] = (x >= 0.f) ? x : 0.01f * x;
    }
  }
}

// ---------------------------------------------------------------------------
extern "C" void kernel_launch(void* const* d_in, const int* in_sizes, int n_in,
                              void* d_out, int out_size, void* d_ws, size_t ws_size,
                              hipStream_t stream) {
  (void)in_sizes; (void)n_in; (void)out_size; (void)ws_size;

  const float* text    = (const float*)d_in[0];
  const float* time_in = (const float*)d_in[1];
  const float* Wdw     = (const float*)d_in[2];
  const float* Wdb     = (const float*)d_in[3];
  const float* Wallw   = (const float*)d_in[4];
  const float* Wallb   = (const float*)d_in[5];
  const float* Uallw   = (const float*)d_in[6];
  const float* Uallb   = (const float*)d_in[7];
  const float* tW1w    = (const float*)d_in[8];
  const float* tW1b    = (const float*)d_in[9];
  const float* tW2w    = (const float*)d_in[10];
  const float* tW2b    = (const float*)d_in[11];
  const float* tVw     = (const float*)d_in[12];
  const float* tVb     = (const float*)d_in[13];
  const float* ihw     = (const float*)d_in[14];
  const float* ihb     = (const float*)d_in[15];
  const float* hhb     = (const float*)d_in[16];
  const float* dW1w    = (const float*)d_in[17];
  const float* dW1b    = (const float*)d_in[18];
  const float* dW2w    = (const float*)d_in[19];
  const float* dW2b    = (const float*)d_in[20];
  const float* dVw     = (const float*)d_in[21];
  const float* dVb     = (const float*)d_in[22];
  const float* predw   = (const float*)d_in[23];
  const float* predb   = (const float*)d_in[24];

  float* ws      = (float*)d_ws;
  float* u       = ws;                                // S*300*256 f32
  float* full    = u + (size_t)NS * NM * NG;          // S*L*T*H  f32
  float* day_vec = full + (size_t)NS * NL * NT * NH;  // S*L*H    f32
  half_t* Af16   = (half_t*)(day_vec + (size_t)NS * NL * NH); // S*320*768 f16
  half_t* Bf16   = Af16 + (size_t)NS * MPAD * NE;             // S*256*768 f16

  convA_kernel<<<(NS * MPAD * NE) / (8 * 256), 256, 0, stream>>>(text, Af16);
  convB_kernel<<<NS * 192, 256, 0, stream>>>(Uallw, Bf16);
  gemm_mfma_kernel<<<NS * 10, 256, 0, stream>>>(Af16, Bf16, Uallb, u);
  time_lstm_kernel<<<NS * NL, 64, 0, stream>>>(u, time_in, Wdw, Wdb,
                                               Wallw, Wallb, full);
  text_attn_kernel<<<NS * NL, 64, 0, stream>>>(full, tW1w, tW1b, tW2w, tW2b,
                                               tVw, tVb, day_vec);
  day_head_kernel<<<NS, 256, 0, stream>>>(day_vec, ihw, ihb, hhb,
                                          dW1w, dW1b, dW2w, dW2b, dVw, dVb,
                                          predw, predb, (float*)d_out);
}

// Round 7
// 104.733 us; speedup vs baseline: 4.1663x; 1.3206x over previous
//
#include <hip/hip_runtime.h>
#include <cmath>

#define NS 88
#define NL 10
#define NT 30
#define NE 768
#define NH 64
#define NG 256   // 4*H
#define NM 300   // L*T

typedef _Float16 half_t;
typedef __attribute__((ext_vector_type(2))) _Float16 half2_t;
typedef __attribute__((ext_vector_type(8))) _Float16 half8;
typedef __attribute__((ext_vector_type(4))) _Float16 half4v;
typedef __attribute__((ext_vector_type(4))) float f32x4;

__device__ inline void gload_lds16(const void* g, void* l) {
  __builtin_amdgcn_global_load_lds(
      (const __attribute__((address_space(1))) unsigned int*)g,
      (__attribute__((address_space(3))) unsigned int*)l, 16, 0, 0);
}

// fast sigmoid/tanh: v_exp_f32 + v_rcp_f32
__device__ inline float fsigmoid(float x) {
  return __builtin_amdgcn_rcpf(1.f + __expf(-x));
}
__device__ inline float ftanh(float x) {
  float e = __expf(2.f * x);
  return 1.f - 2.f * __builtin_amdgcn_rcpf(e + 1.f);
}

#if __has_builtin(__builtin_amdgcn_fdot2)
__device__ inline float fdot2(half2_t a, half2_t b, float c) {
  return __builtin_amdgcn_fdot2(a, b, c, false);   // v_dot2_f32_f16
}
#else
__device__ inline float fdot2(half2_t a, half2_t b, float c) {
  return fmaf((float)a[1], (float)b[1], fmaf((float)a[0], (float)b[0], c));
}
#endif

__device__ inline half2_t mk_h2(float a, float b) {
  half2_t r; r[0] = (half_t)a; r[1] = (half_t)b; return r;
}

// ---------------------------------------------------------------------------
// convB: Uall_w fp32 [S,768,256] -> fp16 transposed [S,256,768] (n-major,
// k contiguous). LDS 32x32 tile transpose. Grid: S * 24 * 8 blocks.
// ---------------------------------------------------------------------------
__global__ __launch_bounds__(256) void convB_kernel(
    const float* __restrict__ in, half_t* __restrict__ out)
{
  __shared__ float tile[32][36];
  int b  = blockIdx.x;
  int s  = b / 192;
  int r  = b % 192;
  int kt = r / 8;
  int nt = r % 8;
  int t  = threadIdx.x;

  int kk  = t >> 3;
  int nn4 = (t & 7) * 4;
  float4 v = *(const float4*)(in + ((size_t)s * NE + kt * 32 + kk) * NG + nt * 32 + nn4);
  tile[kk][nn4 + 0] = v.x; tile[kk][nn4 + 1] = v.y;
  tile[kk][nn4 + 2] = v.z; tile[kk][nn4 + 3] = v.w;
  __syncthreads();

  int nn = t >> 3;
  int kq = (t & 7) * 4;
  half4v o;
#pragma unroll
  for (int j = 0; j < 4; ++j) o[j] = (half_t)tile[kq + j][nn];
  *(half4v*)(out + ((size_t)s * NG + nt * 32 + nn) * NE + kt * 32 + kq) = o;
}

// ---------------------------------------------------------------------------
// gemm_mfma (convA FUSED): U[s,m,n] = text[s,m,:] . Bf16[s,n,:] + bias[s,n]
// A staged from text f32 directly: global f32 load -> cvt f16 -> ds_write
// into the XOR-swizzled layout (chunk c at slot c^(row&7) — same involution
// the fragment reads use). B staged via global_load_lds from convB output.
// 64m x 128n tile, 4 waves (2m x 2n), BK=64, 12 K-steps.
// ---------------------------------------------------------------------------
__global__ __launch_bounds__(256) void gemm_mfma_kernel(
    const float*  __restrict__ text,  // [S,300,768] f32
    const half_t* __restrict__ Bf16,  // [S,256,768] f16 (n-major, k contig)
    const float*  __restrict__ bias,  // [S,256]
    float* __restrict__ U)            // [S,300,256]
{
  __shared__ uint4 smem4[1536];       // 24 KiB: A 8K @0, B 16K @8192
  char* smem = (char*)smem4;

  int b   = blockIdx.x;
  int swz = (b & 7) * 110 + (b >> 3);   // 880 = 8*110, bijective XCD swizzle
  int s   = swz / 10;
  int rr_ = swz % 10;
  int m0  = (rr_ >> 1) * 64;            // 0..256 (rows 300..319 zero-padded)
  int n0  = (rr_ & 1) * 128;

  int tid = threadIdx.x;
  int w = tid >> 6, l = tid & 63;
  int wm = w >> 1, wn = w & 1;
  int lr = l & 15, lk = l >> 4;       // fragment row, k-group

  const float*  At = text + (size_t)s * NM * NE;
  const half_t* Bb = Bf16 + ((size_t)s * NG + n0) * NE;

  f32x4 acc[2][4];
#pragma unroll
  for (int i = 0; i < 2; ++i)
#pragma unroll
    for (int j = 0; j < 4; ++j) acc[i][j] = (f32x4){0.f, 0.f, 0.f, 0.f};

  for (int step = 0; step < 12; ++step) {
    int k0 = step * 64;
    // stage B: 128 rows x 64 k = 16KB (4 gload calls), inverse-swz source
#pragma unroll
    for (int j = 0; j < 4; ++j) {
      int ci  = j * 256 + tid;
      int row = ci >> 3;
      int c   = (ci & 7) ^ (row & 7);
      gload_lds16(Bb + (size_t)row * NE + k0 + c * 8,
                  smem + 8192 + j * 4096 + w * 1024);
    }
    // stage A: 64 rows x 64 k, f32 global -> f16 -> swizzled ds_write_b128.
    // lanes 0..7 cover one row's 8 chunks (32B each) -> coalesced 256B.
#pragma unroll
    for (int j = 0; j < 2; ++j) {
      int idx = j * 256 + tid;
      int row = idx >> 3, c = idx & 7;
      int m   = m0 + row;
      half8 av;
      if (m < NM) {
        const float* p = At + (size_t)m * NE + k0 + c * 8;
        float4 x = *(const float4*)p;
        float4 y = *(const float4*)(p + 4);
        av[0] = (half_t)x.x; av[1] = (half_t)x.y;
        av[2] = (half_t)x.z; av[3] = (half_t)x.w;
        av[4] = (half_t)y.x; av[5] = (half_t)y.y;
        av[6] = (half_t)y.z; av[7] = (half_t)y.w;
      } else {
#pragma unroll
        for (int q = 0; q < 8; ++q) av[q] = (half_t)0.f;
      }
      *(half8*)(smem + row * 128 + ((c ^ (row & 7)) * 16)) = av;
    }
    __syncthreads();   // drains vmcnt (gload) + lgkmcnt (ds_write)

#pragma unroll
    for (int kk = 0; kk < 2; ++kk) {
      half8 af[2], bf[4];
#pragma unroll
      for (int fm = 0; fm < 2; ++fm) {
        int rw = wm * 32 + fm * 16 + lr;
        int cc = (kk * 4 + lk) ^ (rw & 7);
        af[fm] = *(const half8*)(smem + rw * 128 + cc * 16);
      }
#pragma unroll
      for (int fn = 0; fn < 4; ++fn) {
        int rw = wn * 64 + fn * 16 + lr;
        int cc = (kk * 4 + lk) ^ (rw & 7);
        bf[fn] = *(const half8*)(smem + 8192 + rw * 128 + cc * 16);
      }
#pragma unroll
      for (int fm = 0; fm < 2; ++fm)
#pragma unroll
        for (int fn = 0; fn < 4; ++fn)
          acc[fm][fn] = __builtin_amdgcn_mfma_f32_16x16x32_f16(
              af[fm], bf[fn], acc[fm][fn], 0, 0, 0);
    }
    __syncthreads();
  }

  // epilogue: D row = lk*4+e, col = lr (m89 layout); add bias, f32 store
#pragma unroll
  for (int fn = 0; fn < 4; ++fn) {
    int col = n0 + wn * 64 + fn * 16 + lr;
    float bv = bias[(size_t)s * NG + col];
#pragma unroll
    for (int fm = 0; fm < 2; ++fm) {
      int mbase = m0 + wm * 32 + fm * 16 + lk * 4;
#pragma unroll
      for (int e = 0; e < 4; ++e) {
        int m = mbase + e;
        if (m < NM)
          U[((size_t)s * NM + m) * NG + col] = acc[fm][fn][e] + bv;
      }
    }
  }
}

// ---------------------------------------------------------------------------
// TimeLSTM + text attention FUSED. One wave per (stock, day) — barrier-free.
// Scan: lane j owns h[j],c[j]; Wall cols {j,64+j,128+j,192+j} + Wd col j as
// packed f16 pairs (v_dot2_f32_f16, f32 accumulate); h/c broadcast via LDS
// f16 (single-wave, ds-ordering only). h history kept in LDS (f32).
// Attention: same wave computes scores (tw2 col in regs, float4 hist reads,
// shfl-xor reduce), in-register softmax over T, writes day_vec directly.
// No `full` buffer, no separate text_attn kernel.
// ---------------------------------------------------------------------------
__global__ __launch_bounds__(64) void lstm_attn_kernel(
    const float* __restrict__ u,       // [S, L*T, 256] f32
    const float* __restrict__ time_in, // [S, L, T]
    const float* __restrict__ Wdw,  const float* __restrict__ Wdb,
    const float* __restrict__ Wallw, const float* __restrict__ Wallb,
    const float* __restrict__ tW1w, const float* __restrict__ tW1b,
    const float* __restrict__ tW2w, const float* __restrict__ tW2b,
    const float* __restrict__ tVw,  const float* __restrict__ tVb,
    float* __restrict__ day_vec)       // [S, L, H]
{
  int bid = blockIdx.x;                // s*NL + l
  int s = bid / NL;
  int j = threadIdx.x;                 // 0..63

  __shared__ float   u_s[NT * NG];     // 30 KiB
  __shared__ float   hist[NT][NH];     // 7.5 KiB
  __shared__ float   ts_s[NT];
  __shared__ half2_t h2_s[NH / 2];
  __shared__ half2_t c2_s[NH / 2];

  // stage u tile: 30 rows x 1KB, per-lane source (lane j -> bytes 16j..16j+16)
  const float* u_base = u + (size_t)bid * NT * NG;
#pragma unroll
  for (int i = 0; i < NT; ++i)
    gload_lds16(u_base + i * NG + j * 4, (char*)u_s + i * 1024);

  if (j < NT) ts_s[j] = time_in[(size_t)bid * NT + j];
  ((half_t*)h2_s)[j] = (half_t)0.f;
  ((half_t*)c2_s)[j] = (half_t)0.f;

  // weights -> packed f16 pairs in VGPRs
  const float* Wa  = Wallw + (size_t)s * NH * NG;
  const float* Wdp = Wdw   + (size_t)s * NH * NH;
  half2_t wf[32], wi[32], wo[32], wg[32], wd[32];
#pragma unroll
  for (int k2 = 0; k2 < 32; ++k2) {
    wf[k2] = mk_h2(Wa[(2*k2) * NG + j],        Wa[(2*k2+1) * NG + j]);
    wi[k2] = mk_h2(Wa[(2*k2) * NG + 64 + j],   Wa[(2*k2+1) * NG + 64 + j]);
    wo[k2] = mk_h2(Wa[(2*k2) * NG + 128 + j],  Wa[(2*k2+1) * NG + 128 + j]);
    wg[k2] = mk_h2(Wa[(2*k2) * NG + 192 + j],  Wa[(2*k2+1) * NG + 192 + j]);
    wd[k2] = mk_h2(Wdp[(2*k2) * NH + j],       Wdp[(2*k2+1) * NH + j]);
  }
  float bf = Wallb[(size_t)s * NG + j];
  float bi = Wallb[(size_t)s * NG + 64 + j];
  float bo = Wallb[(size_t)s * NG + 128 + j];
  float bg = Wallb[(size_t)s * NG + 192 + j];
  float bd = Wdb[(size_t)s * NH + j];

  // drain global_load_lds before reading u_s (single wave: no barrier)
  asm volatile("s_waitcnt vmcnt(0)" ::: "memory");

  float c_my = 0.f;
  for (int t = 0; t < NT; ++t) {
    float accf = bf + u_s[t * NG + j];
    float acci = bi + u_s[t * NG + 64 + j];
    float acco = bo + u_s[t * NG + 128 + j];
    float accg = bg + u_s[t * NG + 192 + j];
    float accd = bd;
#pragma unroll
    for (int k2 = 0; k2 < 32; ++k2) {
      half2_t hv = h2_s[k2];
      half2_t cv = c2_s[k2];
      accf = fdot2(hv, wf[k2], accf);
      acci = fdot2(hv, wi[k2], acci);
      acco = fdot2(hv, wo[k2], acco);
      accg = fdot2(hv, wg[k2], accg);
      accd = fdot2(cv, wd[k2], accd);
    }
    float f  = fsigmoid(accf);          // reference: all-sigmoid gates
    float ii = fsigmoid(acci);
    float o  = fsigmoid(acco);
    float gg = fsigmoid(accg);
    float cadj = c_my + ftanh(accd) * (ts_s[t] - 1.f);
    float cn = fmaf(f, cadj, ii * gg);
    c_my = cn;
    float hn = o * ftanh(cn);
    ((half_t*)h2_s)[j] = (half_t)hn;
    ((half_t*)c2_s)[j] = (half_t)cn;
    hist[t][j] = hn;                    // keep history in LDS (f32)
  }

  // ---- text attention over T (same wave; hist complete, ds-ordered) ----
  const float* tW1p = tW1w + (size_t)s * NH * NH;
  const float* tW2p = tW2w + (size_t)s * NH * NH;

  float tw2c[NH];                       // tW2 column j in regs
#pragma unroll
  for (int h = 0; h < NH; ++h) tw2c[h] = tW2p[(size_t)h * NH + j];

  float a1 = tW1b[(size_t)s * NH + j];
  {
    const float4* h4 = (const float4*)&hist[NT - 1][0];
#pragma unroll
    for (int q = 0; q < NH / 4; ++q) {
      float4 v = h4[q];
      a1 = fmaf(v.x, tW1p[(size_t)(4*q+0) * NH + j], a1);
      a1 = fmaf(v.y, tW1p[(size_t)(4*q+1) * NH + j], a1);
      a1 = fmaf(v.z, tW1p[(size_t)(4*q+2) * NH + j], a1);
      a1 = fmaf(v.w, tW1p[(size_t)(4*q+3) * NH + j], a1);
    }
  }
  float b2k = tW2b[(size_t)s * NH + j];
  float tv  = tVw[(size_t)s * NH + j];
  float tvb = tVb[s];

  float sc[NT];
#pragma unroll
  for (int t = 0; t < NT; ++t) {
    float a2 = b2k;
    const float4* h4 = (const float4*)&hist[t][0];
#pragma unroll
    for (int q = 0; q < NH / 4; ++q) {
      float4 v = h4[q];
      a2 = fmaf(v.x, tw2c[4*q+0], a2);
      a2 = fmaf(v.y, tw2c[4*q+1], a2);
      a2 = fmaf(v.z, tw2c[4*q+2], a2);
      a2 = fmaf(v.w, tw2c[4*q+3], a2);
    }
    float v = ftanh(a1 + a2) * tv;
#pragma unroll
    for (int off = 32; off >= 1; off >>= 1) v += __shfl_xor(v, off);
    sc[t] = v + tvb;
  }
  float mx = sc[0];
#pragma unroll
  for (int t = 1; t < NT; ++t) mx = fmaxf(mx, sc[t]);
  float sum = 0.f;
#pragma unroll
  for (int t = 0; t < NT; ++t) { sc[t] = __expf(sc[t] - mx); sum += sc[t]; }
  float inv = __builtin_amdgcn_rcpf(sum);
  float dv = 0.f;
#pragma unroll
  for (int t = 0; t < NT; ++t) dv = fmaf(sc[t] * inv, hist[t][j], dv);
  day_vec[(size_t)bid * NH + j] = dv;
}

// ---------------------------------------------------------------------------
// day LSTM + day attention + pred head. One block per stock.
// ---------------------------------------------------------------------------
__global__ __launch_bounds__(256) void day_head_kernel(
    const float* __restrict__ day_vec, // [S, L, H]
    const float* __restrict__ ihw, const float* __restrict__ ihb,
    const float* __restrict__ hhb,
    const float* __restrict__ dW1w, const float* __restrict__ dW1b,
    const float* __restrict__ dW2w, const float* __restrict__ dW2b,
    const float* __restrict__ dVw,  const float* __restrict__ dVb,
    const float* __restrict__ predw, const float* __restrict__ predb,
    float* __restrict__ out)           // [S]
{
  int s = blockIdx.x;
  int g = threadIdx.x;
  int j = g & 63;
  int q = g >> 6;

  __shared__ float dv_s[NL][NH];
  __shared__ float gl[NL][NG];
  __shared__ float hd[NL][NH];

  for (int i = g; i < NL * NH; i += 256)
    ((float*)dv_s)[i] = day_vec[(size_t)s * NL * NH + i];
  __syncthreads();

  float ihcol[NH];
#pragma unroll
  for (int k = 0; k < NH; ++k)
    ihcol[k] = ihw[((size_t)s * NH + k) * NG + g];
  float bias = ihb[(size_t)s * NG + g] + hhb[(size_t)s * NG + g];

  bool is_gpart = (g >= 128 && g < 192);
  for (int l = 0; l < NL; ++l) {
    float acc = bias;
#pragma unroll
    for (int k = 0; k < NH; ++k) acc = fmaf(dv_s[l][k], ihcol[k], acc);
    gl[l][g] = is_gpart ? ftanh(acc) : fsigmoid(acc);
  }
  __syncthreads();
  for (int l = q; l < NL; l += 4) {
    float cd = gl[l][j] * gl[l][128 + j];       // sig(i)*tanh(g)
    hd[l][j] = gl[l][192 + j] * ftanh(cd);      // sig(o)*tanh(c)
  }
  __syncthreads();

  if (g < 64) {
    int k = g;
    float dw1c[NH], dw2c[NH];
#pragma unroll
    for (int h = 0; h < NH; ++h) {
      dw1c[h] = dW1w[((size_t)s * NH + h) * NH + k];
      dw2c[h] = dW2w[((size_t)s * NH + h) * NH + k];
    }
    float b1 = dW1b[(size_t)s * NH + k];
    float b2 = dW2b[(size_t)s * NH + k];
    float dv = dVw[(size_t)s * NH + k];
    float dvb = dVb[s];

    float sc[NL];
#pragma unroll
    for (int l = 0; l < NL; ++l) {
      float x1 = b1, x2 = b2;
#pragma unroll
      for (int h = 0; h < NH; ++h) {
        x1 = fmaf(hd[l][h], dw1c[h], x1);
        x2 = fmaf(hd[l][h], dw2c[h], x2);
      }
      float v = ftanh(x1 + x2) * dv;
#pragma unroll
      for (int off = 32; off >= 1; off >>= 1) v += __shfl_xor(v, off);
      sc[l] = v + dvb;
    }
    float mx = sc[0];
#pragma unroll
    for (int l = 1; l < NL; ++l) mx = fmaxf(mx, sc[l]);
    float sum = 0.f;
#pragma unroll
    for (int l = 0; l < NL; ++l) { sc[l] = __expf(sc[l] - mx); sum += sc[l]; }
    float inv = __builtin_amdgcn_rcpf(sum);
    float sv = 0.f;
#pragma unroll
    for (int l = 0; l < NL; ++l) sv = fmaf(sc[l] * inv, hd[l][k], sv);

    float p = sv * predw[k];
#pragma unroll
    for (int off = 32; off >= 1; off >>= 1) p += __shfl_xor(p, off);
    if (k == 0) {
      float x = p + predb[0];
      out[s] = (x >= 0.f) ? x : 0.01f * x;
    }
  }
}

// ---------------------------------------------------------------------------
extern "C" void kernel_launch(void* const* d_in, const int* in_sizes, int n_in,
                              void* d_out, int out_size, void* d_ws, size_t ws_size,
                              hipStream_t stream) {
  (void)in_sizes; (void)n_in; (void)out_size; (void)ws_size;

  const float* text    = (const float*)d_in[0];
  const float* time_in = (const float*)d_in[1];
  const float* Wdw     = (const float*)d_in[2];
  const float* Wdb     = (const float*)d_in[3];
  const float* Wallw   = (const float*)d_in[4];
  const float* Wallb   = (const float*)d_in[5];
  const float* Uallw   = (const float*)d_in[6];
  const float* Uallb   = (const float*)d_in[7];
  const float* tW1w    = (const float*)d_in[8];
  const float* tW1b    = (const float*)d_in[9];
  const float* tW2w    = (const float*)d_in[10];
  const float* tW2b    = (const float*)d_in[11];
  const float* tVw     = (const float*)d_in[12];
  const float* tVb     = (const float*)d_in[13];
  const float* ihw     = (const float*)d_in[14];
  const float* ihb     = (const float*)d_in[15];
  const float* hhb     = (const float*)d_in[16];
  const float* dW1w    = (const float*)d_in[17];
  const float* dW1b    = (const float*)d_in[18];
  const float* dW2w    = (const float*)d_in[19];
  const float* dW2b    = (const float*)d_in[20];
  const float* dVw     = (const float*)d_in[21];
  const float* dVb     = (const float*)d_in[22];
  const float* predw   = (const float*)d_in[23];
  const float* predb   = (const float*)d_in[24];

  float* ws      = (float*)d_ws;
  float* u       = ws;                                // S*300*256 f32
  float* day_vec = u + (size_t)NS * NM * NG;          // S*L*H    f32
  half_t* Bf16   = (half_t*)(day_vec + (size_t)NS * NL * NH); // S*256*768 f16

  convB_kernel<<<NS * 192, 256, 0, stream>>>(Uallw, Bf16);
  gemm_mfma_kernel<<<NS * 10, 256, 0, stream>>>(text, Bf16, Uallb, u);
  lstm_attn_kernel<<<NS * NL, 64, 0, stream>>>(u, time_in, Wdw, Wdb,
                                               Wallw, Wallb,
                                               tW1w, tW1b, tW2w, tW2b,
                                               tVw, tVb, day_vec);
  day_head_kernel<<<NS, 256, 0, stream>>>(day_vec, ihw, ihb, hhb,
                                          dW1w, dW1b, dW2w, dW2b, dVw, dVb,
                                          predw, predb, (float*)d_out);
}